// Round 5
// baseline (412.915 us; speedup 1.0000x reference)
//
#include <hip/hip_runtime.h>

// Sizes: N=2, M=512, D_IN=64, D=128, H=8. Rows = N*M = 1024.
// ALL fp32: inputs are f32 (proven: bf16 misread NaN'd; converted run gave small
// finite error), so reference outputs are f32 and d_out is read as float32.
// Intermediates in static __device__ globals (no ws_size dependence); every
// element rewritten each launch before use.
__device__ __align__(16) float g_h[1024 * 128];
__device__ __align__(16) float g_K[8 * 1024 * 128];
__device__ __align__(16) float g_Q[8 * 1024 * 128];
__device__ __align__(16) float g_V[8 * 1024 * 128];
__device__ __align__(16) float g_att[1024 * 1024];
__device__ __align__(16) float g_A[1024 * 128];
__device__ __align__(16) float g_Bm[1024 * 128];

// ---------------- Kernel 1: f_node  h = relu((x+te)@w1+b1)@w2+b2 ----------------
__global__ void k_fnode(const float* __restrict__ x, const float* __restrict__ w1,
                        const float* __restrict__ b1, const float* __restrict__ w2,
                        const float* __restrict__ b2) {
  int row = blockIdx.x, tx = threadIdx.x;
  __shared__ float xr[64];
  __shared__ float hid[256];
  __shared__ float part[256];
  if (tx < 64) xr[tx] = x[row * 64 + tx] + sinf((float)tx * (5.0f / 63.0f));
  __syncthreads();
  float acc = b1[tx];
#pragma unroll 8
  for (int k = 0; k < 64; k++) acc = fmaf(xr[k], w1[k * 256 + tx], acc);
  hid[tx] = fmaxf(acc, 0.0f);
  __syncthreads();
  int e = tx & 127, half = tx >> 7;
  int k0 = half * 128;
  float a2 = 0.0f;
#pragma unroll 8
  for (int k = 0; k < 128; k++) a2 = fmaf(hid[k0 + k], w2[(k0 + k) * 128 + e], a2);
  part[tx] = a2;
  __syncthreads();
  if (tx < 128) g_h[row * 128 + tx] = part[tx] + part[tx + 128] + b2[tx];
}

// ---------------- Kernel 2: K/Q/V projections (tiled GEMM 1024x3072x128) --------
__global__ void k_kqv(const float* __restrict__ wk, const float* __restrict__ bk,
                      const float* __restrict__ wq, const float* __restrict__ bq,
                      const float* __restrict__ wv, const float* __restrict__ bv) {
  int b = blockIdx.x, tx = threadIdx.x;
  int ct = b % 48, rt = b / 48;
  int c0 = ct * 64;
  int proj = c0 >> 10, rem = c0 & 1023, head = rem >> 7, e0 = rem & 127; // e0 in {0,64}
  const float* W  = (proj == 0) ? wk : (proj == 1) ? wq : wv;
  const float* Bb = (proj == 0) ? bk : (proj == 1) ? bq : bv;
  float* O = (proj == 0) ? g_K : (proj == 1) ? g_Q : g_V;
  __shared__ float hs[64 * 129];
  __shared__ float wt[64 * 65];
  int r0 = rt * 64;
#pragma unroll
  for (int t = 0; t < 32; t++) {
    int idx = t * 256 + tx, r = idx >> 7, d = idx & 127;
    hs[r * 129 + d] = g_h[(r0 + r) * 128 + d];
  }
  int rg = tx >> 4, cg = tx & 15;
  float acc[4][4] = {};
  const float* Wh = W + head * 16384 + e0;
  for (int kk = 0; kk < 128; kk += 64) {
    __syncthreads();
#pragma unroll
    for (int t = 0; t < 16; t++) {
      int idx = t * 256 + tx, k = idx >> 6, j = idx & 63;
      wt[k * 65 + j] = Wh[(kk + k) * 128 + j];
    }
    __syncthreads();
    const float* h0 = &hs[(rg * 4) * 129 + kk];
#pragma unroll 4
    for (int d = 0; d < 64; d++) {
      float a0 = h0[d];
      float a1 = h0[129 + d];
      float a2 = h0[258 + d];
      float a3 = h0[387 + d];
      const float* wp = &wt[d * 65 + cg * 4];
      float b0 = wp[0], b1v = wp[1], b2v = wp[2], b3v = wp[3];
      acc[0][0] = fmaf(a0, b0, acc[0][0]); acc[0][1] = fmaf(a0, b1v, acc[0][1]);
      acc[0][2] = fmaf(a0, b2v, acc[0][2]); acc[0][3] = fmaf(a0, b3v, acc[0][3]);
      acc[1][0] = fmaf(a1, b0, acc[1][0]); acc[1][1] = fmaf(a1, b1v, acc[1][1]);
      acc[1][2] = fmaf(a1, b2v, acc[1][2]); acc[1][3] = fmaf(a1, b3v, acc[1][3]);
      acc[2][0] = fmaf(a2, b0, acc[2][0]); acc[2][1] = fmaf(a2, b1v, acc[2][1]);
      acc[2][2] = fmaf(a2, b2v, acc[2][2]); acc[2][3] = fmaf(a2, b3v, acc[2][3]);
      acc[3][0] = fmaf(a3, b0, acc[3][0]); acc[3][1] = fmaf(a3, b1v, acc[3][1]);
      acc[3][2] = fmaf(a3, b2v, acc[3][2]); acc[3][3] = fmaf(a3, b3v, acc[3][3]);
    }
  }
#pragma unroll
  for (int ri = 0; ri < 4; ri++) {
    int grow = r0 + rg * 4 + ri;
    int eb = e0 + cg * 4;
    float4 st;
    st.x = acc[ri][0] + Bb[head * 128 + eb + 0];
    st.y = acc[ri][1] + Bb[head * 128 + eb + 1];
    st.z = acc[ri][2] + Bb[head * 128 + eb + 2];
    st.w = acc[ri][3] + Bb[head * 128 + eb + 3];
    *(float4*)&O[(head * 1024 + grow) * 128 + eb] = st;
  }
}

// ---------------- Kernel 3: attention, flash-style online softmax ----------------
// scores[i,j] = K_i . Q_j ; softmax over j of leaky(scores); O = leaky(P@V / l).
__global__ void k_attn() {
  int b = blockIdx.x, tx = threadIdx.x;
  int it = b & 15, hn = b >> 4;            // hn = h*2 + n
  __shared__ float Ks[32 * 132];
  __shared__ float QVs[64 * 132];
  __shared__ float Ss[32 * 68];
  const float* Kp = g_K + hn * 512 * 128;
  const float* Qp = g_Q + hn * 512 * 128;
  const float* Vp = g_V + hn * 512 * 128;
  int i0 = it * 32;
#pragma unroll
  for (int t = 0; t < 16; t++) {
    int idx = t * 256 + tx, r = idx >> 7, d = idx & 127;
    Ks[r * 132 + d] = Kp[(i0 + r) * 128 + d];
  }
  int rg = tx >> 5;   // 0..7  -> rows rg*4 + 0..3
  int cg = tx & 31;   // 0..31
  float o[4][4] = {};
  float mrow[4], lrow[4];
#pragma unroll
  for (int ri = 0; ri < 4; ri++) { mrow[ri] = -1e30f; lrow[ri] = 0.0f; }

  for (int jt = 0; jt < 8; jt++) {
    int j0 = jt * 64;
    __syncthreads();  // prior PV reads of QVs/Ss done (covers Ks staging at jt=0)
#pragma unroll
    for (int t = 0; t < 32; t++) {
      int idx = t * 256 + tx, r = idx >> 7, d = idx & 127;
      QVs[r * 132 + d] = Qp[(j0 + r) * 128 + d];
    }
    __syncthreads();
    // --- S = K Q^T (4 rows x 2 cols per thread) ---
    float s[4][2] = {};
#pragma unroll 4
    for (int dc = 0; dc < 32; dc++) {
      float4 k4[4];
#pragma unroll
      for (int ri = 0; ri < 4; ri++)
        k4[ri] = *(const float4*)&Ks[(rg * 4 + ri) * 132 + dc * 4];
#pragma unroll
      for (int cj = 0; cj < 2; cj++) {
        const float* qq = &QVs[(cg * 2 + cj) * 132 + dc * 4];
        float q0 = qq[0], q1 = qq[1], q2 = qq[2], q3 = qq[3];
#pragma unroll
        for (int ri = 0; ri < 4; ri++) {
          s[ri][cj] = fmaf(k4[ri].x, q0, s[ri][cj]);
          s[ri][cj] = fmaf(k4[ri].y, q1, s[ri][cj]);
          s[ri][cj] = fmaf(k4[ri].z, q2, s[ri][cj]);
          s[ri][cj] = fmaf(k4[ri].w, q3, s[ri][cj]);
        }
      }
    }
    // leaky on scores
#pragma unroll
    for (int ri = 0; ri < 4; ri++)
#pragma unroll
      for (int cj = 0; cj < 2; cj++) {
        float v = s[ri][cj];
        s[ri][cj] = fmaxf(v, 0.2f * v);
      }
    // --- online softmax update (reduce across the 32 lanes sharing rows) ---
#pragma unroll
    for (int ri = 0; ri < 4; ri++) {
      float tm = fmaxf(s[ri][0], s[ri][1]);
      for (int off = 1; off < 32; off <<= 1) tm = fmaxf(tm, __shfl_xor(tm, off, 32));
      float mn = fmaxf(mrow[ri], tm);
      float alpha = __expf(mrow[ri] - mn);
      mrow[ri] = mn;
      float p0 = __expf(s[ri][0] - mn), p1 = __expf(s[ri][1] - mn);
      float ps = p0 + p1;
      for (int off = 1; off < 32; off <<= 1) ps += __shfl_xor(ps, off, 32);
      lrow[ri] = lrow[ri] * alpha + ps;
      Ss[(rg * 4 + ri) * 68 + cg * 2 + 0] = p0;
      Ss[(rg * 4 + ri) * 68 + cg * 2 + 1] = p1;
#pragma unroll
      for (int cc = 0; cc < 4; cc++) o[ri][cc] *= alpha;
    }
    __syncthreads();  // Ss visible; S-compute done -> safe to overwrite QVs with V
#pragma unroll
    for (int t = 0; t < 32; t++) {
      int idx = t * 256 + tx, r = idx >> 7, d = idx & 127;
      QVs[r * 132 + d] = Vp[(j0 + r) * 128 + d];
    }
    __syncthreads();
    // --- O += P V (4 rows x 4 cols per thread) ---
    for (int j4 = 0; j4 < 64; j4 += 4) {
      float p[4][4];
#pragma unroll
      for (int ri = 0; ri < 4; ri++)
        *(float4*)p[ri] = *(const float4*)&Ss[(rg * 4 + ri) * 68 + j4];
#pragma unroll
      for (int jj = 0; jj < 4; jj++) {
        float4 v4 = *(const float4*)&QVs[(j4 + jj) * 132 + cg * 4];
#pragma unroll
        for (int ri = 0; ri < 4; ri++) {
          o[ri][0] = fmaf(p[ri][jj], v4.x, o[ri][0]);
          o[ri][1] = fmaf(p[ri][jj], v4.y, o[ri][1]);
          o[ri][2] = fmaf(p[ri][jj], v4.z, o[ri][2]);
          o[ri][3] = fmaf(p[ri][jj], v4.w, o[ri][3]);
        }
      }
    }
  }
  // epilogue: normalize, leaky, store to concat layout [n,m,h*128+e]
  int hh = hn >> 1, n = hn & 1;
#pragma unroll
  for (int ri = 0; ri < 4; ri++) {
    float inv = 1.0f / lrow[ri];
    float4 st;
    float v0 = o[ri][0] * inv; st.x = fmaxf(v0, 0.2f * v0);
    float v1 = o[ri][1] * inv; st.y = fmaxf(v1, 0.2f * v1);
    float v2 = o[ri][2] * inv; st.z = fmaxf(v2, 0.2f * v2);
    float v3 = o[ri][3] * inv; st.w = fmaxf(v3, 0.2f * v3);
    int grow = n * 512 + i0 + rg * 4 + ri;
    *(float4*)&g_att[grow * 1024 + hh * 128 + cg * 4] = st;
  }
}

// ---------------- Kernel 4: f_v MLP + residual + edge A/B projections ------------
__global__ void k_fv(const float* __restrict__ w1, const float* __restrict__ b1,
                     const float* __restrict__ w2, const float* __restrict__ b2,
                     const float* __restrict__ few1, const float* __restrict__ feb1,
                     float* __restrict__ x2out) {
  int blk = blockIdx.x, tx = threadIdx.x;
  int grow0 = blk * 4;
  __shared__ float atts[4 * 1024];
  __shared__ float hids[4 * 128];
  __shared__ float x2s[4 * 128];
#pragma unroll
  for (int t = 0; t < 16; t++) {
    int idx = t * 256 + tx;
    atts[idx] = g_att[grow0 * 1024 + idx];
  }
  __syncthreads();
  int row = tx >> 6, e0 = (tx & 63) * 2;
  const float* ar = &atts[row * 1024];
  float a0 = b1[e0], a1 = b1[e0 + 1];
#pragma unroll 8
  for (int d = 0; d < 1024; d++) {
    float av = ar[d];
    a0 = fmaf(av, w1[d * 128 + e0], a0);
    a1 = fmaf(av, w1[d * 128 + e0 + 1], a1);
  }
  hids[row * 128 + e0] = fmaxf(a0, 0.0f);
  hids[row * 128 + e0 + 1] = fmaxf(a1, 0.0f);
  __syncthreads();
  float c0 = b2[e0], c1 = b2[e0 + 1];
  const float* hr = &hids[row * 128];
#pragma unroll 8
  for (int k = 0; k < 128; k++) {
    float hv = hr[k];
    c0 = fmaf(hv, w2[k * 128 + e0], c0);
    c1 = fmaf(hv, w2[k * 128 + e0 + 1], c1);
  }
  int gi = (grow0 + row) * 128 + e0;
  c0 += g_h[gi]; c1 += g_h[gi + 1];
  x2s[row * 128 + e0] = c0; x2s[row * 128 + e0 + 1] = c1;
  x2out[gi] = c0; x2out[gi + 1] = c1;
  __syncthreads();
  const float* xr = &x2s[row * 128];
  float aA0 = feb1[e0], aA1 = feb1[e0 + 1];
  float aB0 = 0.0f, aB1 = 0.0f;
#pragma unroll 8
  for (int k = 0; k < 128; k++) {
    float xv = xr[k];
    aA0 = fmaf(xv, few1[k * 128 + e0], aA0);
    aA1 = fmaf(xv, few1[k * 128 + e0 + 1], aA1);
    aB0 = fmaf(xv, few1[(128 + k) * 128 + e0], aB0);
    aB1 = fmaf(xv, few1[(128 + k) * 128 + e0 + 1], aB1);
  }
  g_A[gi] = aA0; g_A[gi + 1] = aA1;
  g_Bm[gi] = aB0; g_Bm[gi + 1] = aB1;
}

// ---------------- Kernel 5: pairwise edge FFN (A_i + B_j factorized) -------------
// edge[n,i,j] = (sum_d relu(A[n,i,d]+B[n,j,d]) * w2[d] + b2) / 512
__global__ void k_edge(const float* __restrict__ few2, const float* __restrict__ feb2,
                       float* __restrict__ edge) {
  int b = blockIdx.x, tx = threadIdx.x;
  int n = b >> 7, i0 = (b & 127) * 4;
  __shared__ float As[4 * 128];
  __shared__ float w2s[128];
  if (tx < 128) w2s[tx] = few2[tx];
  As[tx] = g_A[(n * 512 + i0) * 128 + tx];
  As[tx + 256] = g_A[(n * 512 + i0) * 128 + tx + 256];
  float eb2 = feb2[0];
  __syncthreads();
  int j0 = tx, j1 = tx + 256;
  const float* B0 = &g_Bm[(n * 512 + j0) * 128];
  const float* B1 = &g_Bm[(n * 512 + j1) * 128];
  float acc[2][4] = {};
#pragma unroll 4
  for (int dc = 0; dc < 32; dc++) {
    float4 bv0 = *(const float4*)&B0[dc * 4];
    float4 bv1 = *(const float4*)&B1[dc * 4];
    float4 w4 = *(const float4*)&w2s[dc * 4];
#pragma unroll
    for (int i = 0; i < 4; i++) {
      float4 a4 = *(const float4*)&As[i * 128 + dc * 4];
      acc[0][i] = fmaf(fmaxf(a4.x + bv0.x, 0.0f), w4.x, acc[0][i]);
      acc[0][i] = fmaf(fmaxf(a4.y + bv0.y, 0.0f), w4.y, acc[0][i]);
      acc[0][i] = fmaf(fmaxf(a4.z + bv0.z, 0.0f), w4.z, acc[0][i]);
      acc[0][i] = fmaf(fmaxf(a4.w + bv0.w, 0.0f), w4.w, acc[0][i]);
      acc[1][i] = fmaf(fmaxf(a4.x + bv1.x, 0.0f), w4.x, acc[1][i]);
      acc[1][i] = fmaf(fmaxf(a4.y + bv1.y, 0.0f), w4.y, acc[1][i]);
      acc[1][i] = fmaf(fmaxf(a4.z + bv1.z, 0.0f), w4.z, acc[1][i]);
      acc[1][i] = fmaf(fmaxf(a4.w + bv1.w, 0.0f), w4.w, acc[1][i]);
    }
  }
  const float scale = 1.0f / 512.0f;
#pragma unroll
  for (int i = 0; i < 4; i++) {
    int ri = n * 512 + i0 + i;
    edge[ri * 512 + j0] = (acc[0][i] + eb2) * scale;
    edge[ri * 512 + j1] = (acc[1][i] + eb2) * scale;
  }
}

extern "C" void kernel_launch(void* const* d_in, const int* in_sizes, int n_in,
                              void* d_out, int out_size, void* d_ws, size_t ws_size,
                              hipStream_t stream) {
  (void)in_sizes; (void)n_in; (void)out_size; (void)d_ws; (void)ws_size;
  const float* x     = (const float*)d_in[0];
  const float* fn_w1 = (const float*)d_in[1];
  const float* fn_b1 = (const float*)d_in[2];
  const float* fn_w2 = (const float*)d_in[3];
  const float* fn_b2 = (const float*)d_in[4];
  const float* wk    = (const float*)d_in[5];
  const float* bk    = (const float*)d_in[6];
  const float* wq    = (const float*)d_in[7];
  const float* bq    = (const float*)d_in[8];
  const float* wv    = (const float*)d_in[9];
  const float* bv    = (const float*)d_in[10];
  const float* fv_w1 = (const float*)d_in[11];
  const float* fv_b1 = (const float*)d_in[12];
  const float* fv_w2 = (const float*)d_in[13];
  const float* fv_b2 = (const float*)d_in[14];
  const float* fe_w1 = (const float*)d_in[15];
  const float* fe_b1 = (const float*)d_in[16];
  const float* fe_w2 = (const float*)d_in[17];
  const float* fe_b2 = (const float*)d_in[18];

  float* x2out = (float*)d_out;      // [0, 131072) floats
  float* edge  = x2out + 131072;     // [131072, 655360) floats

  k_fnode<<<1024, 256, 0, stream>>>(x, fn_w1, fn_b1, fn_w2, fn_b2);
  k_kqv<<<768, 256, 0, stream>>>(wk, bk, wq, bq, wv, bv);
  k_attn<<<256, 256, 0, stream>>>();
  k_fv<<<256, 256, 0, stream>>>(fv_w1, fv_b1, fv_w2, fv_b2, fe_w1, fe_b1, x2out);
  k_edge<<<256, 256, 0, stream>>>(fe_w2, fe_b2, edge);
}

// Round 6
// 220.146 us; speedup vs baseline: 1.8756x; 1.8756x over previous
//
#include <hip/hip_runtime.h>

typedef unsigned short u16;
typedef unsigned int u32;

__device__ __forceinline__ u16 f2b(float f) {
  union { float f; u32 i; } v; v.f = f;
  u32 i = v.i;
  return (u16)((i + 0x7FFFu + ((i >> 16) & 1u)) >> 16);
}
__device__ __forceinline__ float lo16(u32 x) { union { u32 i; float f; } v; v.i = x << 16; return v.f; }
__device__ __forceinline__ float hi16(u32 x) { union { u32 i; float f; } v; v.i = x & 0xffff0000u; return v.f; }
__device__ __forceinline__ u32 pack2(float a, float b) { return (u32)f2b(a) | ((u32)f2b(b) << 16); }

// Sizes: N=2, M=512, D_IN=64, D=128, H=8. Rows = N*M = 1024. hn = h*2+n in [0,16).
__device__ __align__(16) float g_h[1024 * 128];
__device__ __align__(16) u16   g_K[16 * 512 * 128];   // bf16 [hn][m][d]
__device__ __align__(16) u16   g_Q[16 * 512 * 128];
__device__ __align__(16) u16   g_V[16 * 512 * 128];
__device__ __align__(16) float g_Op[512 * 64 * 128];  // flash partials per (hn,it,jc) block
__device__ __align__(16) float g_ml[512 * 64 * 2];
__device__ __align__(16) u16   g_att[1024 * 1024];    // bf16 concat [n*512+m][h*128+e]
__device__ __align__(16) float g_A[1024 * 128];
__device__ __align__(16) float g_Bm[1024 * 128];

// ---------------- Kernel 1: f_node  h = relu((x+te)@w1+b1)@w2+b2 ----------------
__global__ void k_fnode(const float* __restrict__ x, const float* __restrict__ w1,
                        const float* __restrict__ b1, const float* __restrict__ w2,
                        const float* __restrict__ b2) {
  int row = blockIdx.x, tx = threadIdx.x;
  __shared__ float xr[64];
  __shared__ float hid[256];
  __shared__ float part[256];
  if (tx < 64) xr[tx] = x[row * 64 + tx] + sinf((float)tx * (5.0f / 63.0f));
  __syncthreads();
  float acc = b1[tx];
#pragma unroll 8
  for (int k = 0; k < 64; k++) acc = fmaf(xr[k], w1[k * 256 + tx], acc);
  hid[tx] = fmaxf(acc, 0.0f);
  __syncthreads();
  int e = tx & 127, half = tx >> 7;
  int k0 = half * 128;
  float a2 = 0.0f;
#pragma unroll 8
  for (int k = 0; k < 128; k++) a2 = fmaf(hid[k0 + k], w2[(k0 + k) * 128 + e], a2);
  part[tx] = a2;
  __syncthreads();
  if (tx < 128) g_h[row * 128 + tx] = part[tx] + part[tx + 128] + b2[tx];
}

// ---------------- Kernel 2: K/Q/V projections, bf16 outputs ----------------------
__global__ void k_kqv(const float* __restrict__ wk, const float* __restrict__ bk,
                      const float* __restrict__ wq, const float* __restrict__ bq,
                      const float* __restrict__ wv, const float* __restrict__ bv) {
  int b = blockIdx.x, tx = threadIdx.x;
  int ct = b % 48, rt = b / 48;
  int c0 = ct * 64;
  int proj = c0 >> 10, rem = c0 & 1023, head = rem >> 7, e0 = rem & 127;
  const float* W  = (proj == 0) ? wk : (proj == 1) ? wq : wv;
  const float* Bb = (proj == 0) ? bk : (proj == 1) ? bq : bv;
  u16* O = (proj == 0) ? g_K : (proj == 1) ? g_Q : g_V;
  __shared__ float hs[64 * 129];
  __shared__ float wt[64 * 65];
  int r0 = rt * 64;
#pragma unroll
  for (int t = 0; t < 32; t++) {
    int idx = t * 256 + tx, r = idx >> 7, d = idx & 127;
    hs[r * 129 + d] = g_h[(r0 + r) * 128 + d];
  }
  int rg = tx >> 4, cg = tx & 15;
  float acc[4][4] = {};
  const float* Wh = W + head * 16384 + e0;
  for (int kk = 0; kk < 128; kk += 64) {
    __syncthreads();
#pragma unroll
    for (int t = 0; t < 16; t++) {
      int idx = t * 256 + tx, k = idx >> 6, j = idx & 63;
      wt[k * 65 + j] = Wh[(kk + k) * 128 + j];
    }
    __syncthreads();
    const float* h0 = &hs[(rg * 4) * 129 + kk];
#pragma unroll 4
    for (int d = 0; d < 64; d++) {
      float a0 = h0[d], a1 = h0[129 + d], a2 = h0[258 + d], a3 = h0[387 + d];
      const float* wp = &wt[d * 65 + cg * 4];
      float b0 = wp[0], b1v = wp[1], b2v = wp[2], b3v = wp[3];
      acc[0][0] = fmaf(a0, b0, acc[0][0]); acc[0][1] = fmaf(a0, b1v, acc[0][1]);
      acc[0][2] = fmaf(a0, b2v, acc[0][2]); acc[0][3] = fmaf(a0, b3v, acc[0][3]);
      acc[1][0] = fmaf(a1, b0, acc[1][0]); acc[1][1] = fmaf(a1, b1v, acc[1][1]);
      acc[1][2] = fmaf(a1, b2v, acc[1][2]); acc[1][3] = fmaf(a1, b3v, acc[1][3]);
      acc[2][0] = fmaf(a2, b0, acc[2][0]); acc[2][1] = fmaf(a2, b1v, acc[2][1]);
      acc[2][2] = fmaf(a2, b2v, acc[2][2]); acc[2][3] = fmaf(a2, b3v, acc[2][3]);
      acc[3][0] = fmaf(a3, b0, acc[3][0]); acc[3][1] = fmaf(a3, b1v, acc[3][1]);
      acc[3][2] = fmaf(a3, b2v, acc[3][2]); acc[3][3] = fmaf(a3, b3v, acc[3][3]);
    }
  }
#pragma unroll
  for (int ri = 0; ri < 4; ri++) {
    int grow = r0 + rg * 4 + ri;
    int eb = e0 + cg * 4;
    float v0 = acc[ri][0] + Bb[head * 128 + eb + 0];
    float v1 = acc[ri][1] + Bb[head * 128 + eb + 1];
    float v2 = acc[ri][2] + Bb[head * 128 + eb + 2];
    float v3 = acc[ri][3] + Bb[head * 128 + eb + 3];
    uint2 st = make_uint2(pack2(v0, v1), pack2(v2, v3));
    *(uint2*)&O[(head * 1024 + grow) * 128 + eb] = st;
  }
}

// ---------------- Kernel 3: attention, flash partials, bf16 LDS ------------------
// b = hn*32 + it*4 + jc: 64-row i-tile, 128-col j-chunk (2 jt of 64).
// LDS rows are octet-XOR-swizzled for bank-safe b128 access.
#define SWZ(row, oct) ((row) * 136 + (((oct) ^ (((row) >> 1) & 7)) << 3))
__global__ __launch_bounds__(256) void k_attn() {
  __shared__ u16 Ks[64 * 136];
  __shared__ u16 Qs[64 * 136];
  __shared__ u16 Vs[64 * 136];
  __shared__ float Ss[64 * 68];
  int b = blockIdx.x, tx = threadIdx.x;
  int jc = b & 3, it = (b >> 2) & 7, hn = b >> 5;
  int i0 = it * 64;
  const u16* Kp = g_K + hn * 65536;
  const u16* Qp = g_Q + hn * 65536;
  const u16* Vp = g_V + hn * 65536;
#pragma unroll
  for (int t = 0; t < 4; t++) {
    int idx = t * 256 + tx, row = idx >> 4, oct = idx & 15;
    *(uint4*)&Ks[SWZ(row, oct)] = *(const uint4*)&Kp[(i0 + row) * 128 + oct * 8];
  }
  int rg = tx >> 4, cg = tx & 15;
  float o[4][8];
  float m_[4], l_[4];
#pragma unroll
  for (int i = 0; i < 4; i++) {
    m_[i] = -1e30f; l_[i] = 0.0f;
#pragma unroll
    for (int j = 0; j < 8; j++) o[i][j] = 0.0f;
  }
  for (int jt = 0; jt < 2; jt++) {
    int j0 = jc * 128 + jt * 64;
    __syncthreads();  // prior PV reads of Vs/Ss done; covers K staging at jt=0
#pragma unroll
    for (int t = 0; t < 4; t++) {
      int idx = t * 256 + tx, row = idx >> 4, oct = idx & 15;
      *(uint4*)&Qs[SWZ(row, oct)] = *(const uint4*)&Qp[(j0 + row) * 128 + oct * 8];
      *(uint4*)&Vs[SWZ(row, oct)] = *(const uint4*)&Vp[(j0 + row) * 128 + oct * 8];
    }
    __syncthreads();
    // --- S = K Q^T : thread tile rows rg*4..+3, cols cg + 16*cj ---
    float s[4][4] = {};
    for (int oct = 0; oct < 16; oct++) {
      float kf[4][8], qf[4][8];
#pragma unroll
      for (int ri = 0; ri < 4; ri++) {
        uint4 kv = *(const uint4*)&Ks[SWZ(rg * 4 + ri, oct)];
        kf[ri][0] = lo16(kv.x); kf[ri][1] = hi16(kv.x);
        kf[ri][2] = lo16(kv.y); kf[ri][3] = hi16(kv.y);
        kf[ri][4] = lo16(kv.z); kf[ri][5] = hi16(kv.z);
        kf[ri][6] = lo16(kv.w); kf[ri][7] = hi16(kv.w);
      }
#pragma unroll
      for (int cj = 0; cj < 4; cj++) {
        uint4 qv = *(const uint4*)&Qs[SWZ(cg + 16 * cj, oct)];
        qf[cj][0] = lo16(qv.x); qf[cj][1] = hi16(qv.x);
        qf[cj][2] = lo16(qv.y); qf[cj][3] = hi16(qv.y);
        qf[cj][4] = lo16(qv.z); qf[cj][5] = hi16(qv.z);
        qf[cj][6] = lo16(qv.w); qf[cj][7] = hi16(qv.w);
      }
#pragma unroll
      for (int ri = 0; ri < 4; ri++)
#pragma unroll
        for (int cj = 0; cj < 4; cj++)
#pragma unroll
          for (int e = 0; e < 8; e++)
            s[ri][cj] = fmaf(kf[ri][e], qf[cj][e], s[ri][cj]);
    }
    // --- leaky + online softmax (row reduce across the 16 cg lanes) ---
#pragma unroll
    for (int ri = 0; ri < 4; ri++) {
      float tm = -1e30f;
#pragma unroll
      for (int cj = 0; cj < 4; cj++) {
        float v = s[ri][cj];
        v = fmaxf(v, 0.2f * v);
        s[ri][cj] = v;
        tm = fmaxf(tm, v);
      }
      tm = fmaxf(tm, __shfl_xor(tm, 1)); tm = fmaxf(tm, __shfl_xor(tm, 2));
      tm = fmaxf(tm, __shfl_xor(tm, 4)); tm = fmaxf(tm, __shfl_xor(tm, 8));
      float mn = fmaxf(m_[ri], tm);
      float alpha = __expf(m_[ri] - mn);
      m_[ri] = mn;
      float p0 = __expf(s[ri][0] - mn), p1 = __expf(s[ri][1] - mn);
      float p2 = __expf(s[ri][2] - mn), p3 = __expf(s[ri][3] - mn);
      float ps = p0 + p1 + p2 + p3;
      ps += __shfl_xor(ps, 1); ps += __shfl_xor(ps, 2);
      ps += __shfl_xor(ps, 4); ps += __shfl_xor(ps, 8);
      l_[ri] = l_[ri] * alpha + ps;
      int row = rg * 4 + ri;
      Ss[row * 68 + cg +  0] = p0;
      Ss[row * 68 + cg + 16] = p1;
      Ss[row * 68 + cg + 32] = p2;
      Ss[row * 68 + cg + 48] = p3;
#pragma unroll
      for (int c = 0; c < 8; c++) o[ri][c] *= alpha;
    }
    __syncthreads();  // Ss visible to all lanes
    // --- O += P V : thread tile rows rg*4..+3, cols cg*8..+7 ---
    for (int j4 = 0; j4 < 64; j4 += 4) {
      float pv[4][4];
#pragma unroll
      for (int ri = 0; ri < 4; ri++)
        *(float4*)pv[ri] = *(const float4*)&Ss[(rg * 4 + ri) * 68 + j4];
#pragma unroll
      for (int jj = 0; jj < 4; jj++) {
        uint4 vv = *(const uint4*)&Vs[SWZ(j4 + jj, cg)];
        float vf0 = lo16(vv.x), vf1 = hi16(vv.x), vf2 = lo16(vv.y), vf3 = hi16(vv.y);
        float vf4 = lo16(vv.z), vf5 = hi16(vv.z), vf6 = lo16(vv.w), vf7 = hi16(vv.w);
#pragma unroll
        for (int ri = 0; ri < 4; ri++) {
          float p = pv[ri][jj];
          o[ri][0] = fmaf(p, vf0, o[ri][0]); o[ri][1] = fmaf(p, vf1, o[ri][1]);
          o[ri][2] = fmaf(p, vf2, o[ri][2]); o[ri][3] = fmaf(p, vf3, o[ri][3]);
          o[ri][4] = fmaf(p, vf4, o[ri][4]); o[ri][5] = fmaf(p, vf5, o[ri][5]);
          o[ri][6] = fmaf(p, vf6, o[ri][6]); o[ri][7] = fmaf(p, vf7, o[ri][7]);
        }
      }
    }
  }
  // epilogue: write UNNORMALIZED partials + (m,l); merge kernel finishes.
#pragma unroll
  for (int ri = 0; ri < 4; ri++) {
    int row = rg * 4 + ri;
    float4 a = make_float4(o[ri][0], o[ri][1], o[ri][2], o[ri][3]);
    float4 c = make_float4(o[ri][4], o[ri][5], o[ri][6], o[ri][7]);
    *(float4*)&g_Op[(b * 64 + row) * 128 + cg * 8] = a;
    *(float4*)&g_Op[(b * 64 + row) * 128 + cg * 8 + 4] = c;
    if (cg == 0) {
      g_ml[(b * 64 + row) * 2 + 0] = m_[ri];
      g_ml[(b * 64 + row) * 2 + 1] = l_[ri];
    }
  }
}

// ---------------- Kernel 3b: merge 4 j-chunk partials -> g_att (bf16) ------------
__global__ void k_amerge() {
  int b = blockIdx.x, tx = threadIdx.x;
  int hn = b >> 5, ig = b & 31;
  int row = ig * 16 + (tx >> 4);        // i-row within hn, 0..511
  int c8 = (tx & 15) * 8;
  int it = row >> 6, lr = row & 63;
  float mc[4], lc[4];
  float4 oa[4], ob[4];
#pragma unroll
  for (int c = 0; c < 4; c++) {
    int bp = hn * 32 + it * 4 + c;
    float2 ml = *(const float2*)&g_ml[(bp * 64 + lr) * 2];
    mc[c] = ml.x; lc[c] = ml.y;
    oa[c] = *(const float4*)&g_Op[(bp * 64 + lr) * 128 + c8];
    ob[c] = *(const float4*)&g_Op[(bp * 64 + lr) * 128 + c8 + 4];
  }
  float ms = fmaxf(fmaxf(mc[0], mc[1]), fmaxf(mc[2], mc[3]));
  float lsum = 0.0f;
  float ra[8] = {};
#pragma unroll
  for (int c = 0; c < 4; c++) {
    float w = __expf(mc[c] - ms);
    lsum += w * lc[c];
    ra[0] = fmaf(w, oa[c].x, ra[0]); ra[1] = fmaf(w, oa[c].y, ra[1]);
    ra[2] = fmaf(w, oa[c].z, ra[2]); ra[3] = fmaf(w, oa[c].w, ra[3]);
    ra[4] = fmaf(w, ob[c].x, ra[4]); ra[5] = fmaf(w, ob[c].y, ra[5]);
    ra[6] = fmaf(w, ob[c].z, ra[6]); ra[7] = fmaf(w, ob[c].w, ra[7]);
  }
  float inv = 1.0f / lsum;
  u16 pk[8];
#pragma unroll
  for (int e = 0; e < 8; e++) {
    float v = ra[e] * inv;
    v = fmaxf(v, 0.2f * v);           // leaky on attention output
    pk[e] = f2b(v);
  }
  int h = hn >> 1, n = hn & 1;
  uint4 st;
  st.x = (u32)pk[0] | ((u32)pk[1] << 16);
  st.y = (u32)pk[2] | ((u32)pk[3] << 16);
  st.z = (u32)pk[4] | ((u32)pk[5] << 16);
  st.w = (u32)pk[6] | ((u32)pk[7] << 16);
  *(uint4*)&g_att[(n * 512 + row) * 1024 + h * 128 + c8] = st;
}

// ---------------- Kernel 4: f_v MLP + residual + edge A/B projections ------------
// 512 blocks x 2 rows: thread = (row = tx>>7, e = tx&127); weight reads coalesced.
__global__ void k_fv(const float* __restrict__ w1, const float* __restrict__ b1,
                     const float* __restrict__ w2, const float* __restrict__ b2,
                     const float* __restrict__ few1, const float* __restrict__ feb1,
                     float* __restrict__ x2out) {
  __shared__ float atts[2 * 1024];
  __shared__ float hids[2 * 128];
  __shared__ float x2s[2 * 128];
  int blk = blockIdx.x, tx = threadIdx.x;
  int grow0 = blk * 2;
  {
    int row = tx >> 7, o8 = (tx & 127) * 8;
    uint4 av = *(const uint4*)&g_att[(grow0 + row) * 1024 + o8];
    float* dst = &atts[row * 1024 + o8];
    dst[0] = lo16(av.x); dst[1] = hi16(av.x);
    dst[2] = lo16(av.y); dst[3] = hi16(av.y);
    dst[4] = lo16(av.z); dst[5] = hi16(av.z);
    dst[6] = lo16(av.w); dst[7] = hi16(av.w);
  }
  __syncthreads();
  int row = tx >> 7, e = tx & 127;
  const float* ar = &atts[row * 1024];
  float acc = b1[e];
#pragma unroll 8
  for (int d = 0; d < 1024; d++) acc = fmaf(ar[d], w1[d * 128 + e], acc);
  hids[row * 128 + e] = fmaxf(acc, 0.0f);
  __syncthreads();
  float c = b2[e];
  const float* hr = &hids[row * 128];
#pragma unroll 8
  for (int k = 0; k < 128; k++) c = fmaf(hr[k], w2[k * 128 + e], c);
  int gi = (grow0 + row) * 128 + e;
  c += g_h[gi];
  x2s[row * 128 + e] = c;
  x2out[gi] = c;
  __syncthreads();
  const float* xr = &x2s[row * 128];
  float aA = feb1[e], aB = 0.0f;
#pragma unroll 8
  for (int k = 0; k < 128; k++) {
    float xv = xr[k];
    aA = fmaf(xv, few1[k * 128 + e], aA);
    aB = fmaf(xv, few1[(128 + k) * 128 + e], aB);
  }
  g_A[gi] = aA;
  g_Bm[gi] = aB;
}

// ---------------- Kernel 5: pairwise edge FFN (A_i + B_j factorized) -------------
// 512 blocks: (n, 4-row i-tile, j-half of 256); thread owns one j.
__global__ void k_edge(const float* __restrict__ few2, const float* __restrict__ feb2,
                       float* __restrict__ edge) {
  __shared__ float As[4 * 128];
  __shared__ float w2s[128];
  int b = blockIdx.x, tx = threadIdx.x;
  int n = b >> 8, rest = b & 255, ig = rest >> 1, jh = rest & 1;
  int i0 = ig * 4;
  if (tx < 128) w2s[tx] = few2[tx];
  As[tx] = g_A[(n * 512 + i0) * 128 + tx];
  As[tx + 256] = g_A[(n * 512 + i0) * 128 + tx + 256];
  float eb2 = feb2[0];
  __syncthreads();
  int j = jh * 256 + tx;
  const float* B0 = &g_Bm[(n * 512 + j) * 128];
  float acc[4] = {};
#pragma unroll 4
  for (int dc = 0; dc < 32; dc++) {
    float4 bv = *(const float4*)&B0[dc * 4];
    float4 w4 = *(const float4*)&w2s[dc * 4];
#pragma unroll
    for (int i = 0; i < 4; i++) {
      float4 a4 = *(const float4*)&As[i * 128 + dc * 4];
      acc[i] = fmaf(fmaxf(a4.x + bv.x, 0.0f), w4.x, acc[i]);
      acc[i] = fmaf(fmaxf(a4.y + bv.y, 0.0f), w4.y, acc[i]);
      acc[i] = fmaf(fmaxf(a4.z + bv.z, 0.0f), w4.z, acc[i]);
      acc[i] = fmaf(fmaxf(a4.w + bv.w, 0.0f), w4.w, acc[i]);
    }
  }
  const float scale = 1.0f / 512.0f;
#pragma unroll
  for (int i = 0; i < 4; i++)
    edge[(n * 512 + i0 + i) * 512 + j] = (acc[i] + eb2) * scale;
}

extern "C" void kernel_launch(void* const* d_in, const int* in_sizes, int n_in,
                              void* d_out, int out_size, void* d_ws, size_t ws_size,
                              hipStream_t stream) {
  (void)in_sizes; (void)n_in; (void)out_size; (void)d_ws; (void)ws_size;
  const float* x     = (const float*)d_in[0];
  const float* fn_w1 = (const float*)d_in[1];
  const float* fn_b1 = (const float*)d_in[2];
  const float* fn_w2 = (const float*)d_in[3];
  const float* fn_b2 = (const float*)d_in[4];
  const float* wk    = (const float*)d_in[5];
  const float* bk    = (const float*)d_in[6];
  const float* wq    = (const float*)d_in[7];
  const float* bq    = (const float*)d_in[8];
  const float* wv    = (const float*)d_in[9];
  const float* bv    = (const float*)d_in[10];
  const float* fv_w1 = (const float*)d_in[11];
  const float* fv_b1 = (const float*)d_in[12];
  const float* fv_w2 = (const float*)d_in[13];
  const float* fv_b2 = (const float*)d_in[14];
  const float* fe_w1 = (const float*)d_in[15];
  const float* fe_b1 = (const float*)d_in[16];
  const float* fe_w2 = (const float*)d_in[17];
  const float* fe_b2 = (const float*)d_in[18];

  float* x2out = (float*)d_out;      // [0, 131072) floats
  float* edge  = x2out + 131072;     // [131072, 655360) floats

  k_fnode<<<1024, 256, 0, stream>>>(x, fn_w1, fn_b1, fn_w2, fn_b2);
  k_kqv<<<768, 256, 0, stream>>>(wk, bk, wq, bq, wv, bv);
  k_attn<<<512, 256, 0, stream>>>();
  k_amerge<<<512, 256, 0, stream>>>();
  k_fv<<<512, 256, 0, stream>>>(fv_w1, fv_b1, fv_w2, fv_b2, fe_w1, fe_b1, x2out);
  k_edge<<<512, 256, 0, stream>>>(fe_w2, fe_b2, edge);
}

// Round 7
// 189.848 us; speedup vs baseline: 2.1750x; 1.1596x over previous
//
#include <hip/hip_runtime.h>

typedef unsigned short u16;
typedef unsigned int u32;

__device__ __forceinline__ u16 f2b(float f) {
  union { float f; u32 i; } v; v.f = f;
  u32 i = v.i;
  return (u16)((i + 0x7FFFu + ((i >> 16) & 1u)) >> 16);
}
__device__ __forceinline__ float lo16(u32 x) { union { u32 i; float f; } v; v.i = x << 16; return v.f; }
__device__ __forceinline__ float hi16(u32 x) { union { u32 i; float f; } v; v.i = x & 0xffff0000u; return v.f; }
__device__ __forceinline__ u32 pack2(float a, float b) { return (u32)f2b(a) | ((u32)f2b(b) << 16); }

// Sizes: N=2, M=512, D_IN=64, D=128, H=8. Rows = N*M = 1024. hn = h*2+n in [0,16).
__device__ __align__(16) float g_h[1024 * 128];
__device__ __align__(16) u16   g_K[16 * 512 * 128];   // bf16 [hn][m][d]
__device__ __align__(16) u16   g_Q[16 * 512 * 128];
__device__ __align__(16) u16   g_V[16 * 512 * 128];
__device__ __align__(16) float g_Op[512 * 64 * 128];  // flash partials per (hn,it,jc) block
__device__ __align__(16) float g_ml[512 * 64 * 2];
__device__ __align__(16) u16   g_att[1024 * 1024];    // bf16 concat [n*512+m][h*128+e]
__device__ __align__(16) float g_part[2 * 1024 * 128]; // fv1 K-half partials
__device__ __align__(16) float g_A[1024 * 128];
__device__ __align__(16) float g_Bm[1024 * 128];

// ---------------- Kernel 1: f_node, 2 rows/block, float4 weights, K-split --------
__global__ void k_fnode(const float* __restrict__ x, const float* __restrict__ w1,
                        const float* __restrict__ b1, const float* __restrict__ w2,
                        const float* __restrict__ b2) {
  __shared__ float xr[2 * 64];
  __shared__ float hids[2 * 256];
  __shared__ float red[2048];     // stage1: [4][2][256]; stage2: [8][2][128]
  int tx = threadIdx.x;
  int row0 = blockIdx.x * 2;
  if (tx < 128) {
    int r = tx >> 6, k = tx & 63;
    xr[tx] = x[(row0 + r) * 64 + k] + sinf((float)k * (5.0f / 63.0f));
  }
  __syncthreads();
  // stage 1: hid[2][256] = relu((x+te)@w1 + b1), K=64 split 4 ways
  {
    int ks = tx >> 6, cg = tx & 63;
    float acc[2][4] = {};
#pragma unroll 4
    for (int i = 0; i < 16; i++) {
      int k = ks * 16 + i;
      float4 w4 = *(const float4*)&w1[k * 256 + cg * 4];
      float a0 = xr[k], a1 = xr[64 + k];
      acc[0][0] = fmaf(a0, w4.x, acc[0][0]); acc[0][1] = fmaf(a0, w4.y, acc[0][1]);
      acc[0][2] = fmaf(a0, w4.z, acc[0][2]); acc[0][3] = fmaf(a0, w4.w, acc[0][3]);
      acc[1][0] = fmaf(a1, w4.x, acc[1][0]); acc[1][1] = fmaf(a1, w4.y, acc[1][1]);
      acc[1][2] = fmaf(a1, w4.z, acc[1][2]); acc[1][3] = fmaf(a1, w4.w, acc[1][3]);
    }
#pragma unroll
    for (int r = 0; r < 2; r++)
      *(float4*)&red[ks * 512 + r * 256 + cg * 4] = *(float4*)acc[r];
  }
  __syncthreads();
#pragma unroll
  for (int jo = 0; jo < 2; jo++) {
    int o = jo * 256 + tx;
    float s = red[o] + red[512 + o] + red[1024 + o] + red[1536 + o];
    hids[o] = fmaxf(s + b1[o & 255], 0.0f);
  }
  __syncthreads();
  // stage 2: h[2][128] = hid@w2 + b2, K=256 split 8 ways
  {
    int ks = tx >> 5, eg = tx & 31;
    float acc[2][4] = {};
#pragma unroll 4
    for (int i = 0; i < 32; i++) {
      int k = ks * 32 + i;
      float4 w4 = *(const float4*)&w2[k * 128 + eg * 4];
      float a0 = hids[k], a1 = hids[256 + k];
      acc[0][0] = fmaf(a0, w4.x, acc[0][0]); acc[0][1] = fmaf(a0, w4.y, acc[0][1]);
      acc[0][2] = fmaf(a0, w4.z, acc[0][2]); acc[0][3] = fmaf(a0, w4.w, acc[0][3]);
      acc[1][0] = fmaf(a1, w4.x, acc[1][0]); acc[1][1] = fmaf(a1, w4.y, acc[1][1]);
      acc[1][2] = fmaf(a1, w4.z, acc[1][2]); acc[1][3] = fmaf(a1, w4.w, acc[1][3]);
    }
    __syncthreads();  // red reads above done before overwrite
#pragma unroll
    for (int r = 0; r < 2; r++)
      *(float4*)&red[ks * 256 + r * 128 + eg * 4] = *(float4*)acc[r];
  }
  __syncthreads();
  {
    float s = 0.0f;
#pragma unroll
    for (int ks = 0; ks < 8; ks++) s += red[ks * 256 + tx];
    int r = tx >> 7, e = tx & 127;
    g_h[(row0 + r) * 128 + e] = s + b2[e];
  }
}

// ---------------- Kernel 2: K/Q/V projections, bf16 out, vector LDS --------------
__global__ void k_kqv(const float* __restrict__ wk, const float* __restrict__ bk,
                      const float* __restrict__ wq, const float* __restrict__ bq,
                      const float* __restrict__ wv, const float* __restrict__ bv) {
  int b = blockIdx.x, tx = threadIdx.x;
  int ct = b % 48, rt = b / 48;
  int c0 = ct * 64;
  int proj = c0 >> 10, rem = c0 & 1023, head = rem >> 7, e0 = rem & 127;
  const float* W  = (proj == 0) ? wk : (proj == 1) ? wq : wv;
  const float* Bb = (proj == 0) ? bk : (proj == 1) ? bq : bv;
  u16* O = (proj == 0) ? g_K : (proj == 1) ? g_Q : g_V;
  __shared__ float hs[64 * 132];   // 16B-aligned rows
  __shared__ float wt[64 * 68];
  int r0 = rt * 64;
#pragma unroll
  for (int t = 0; t < 32; t++) {
    int idx = t * 256 + tx, r = idx >> 7, d = idx & 127;
    hs[r * 132 + d] = g_h[(r0 + r) * 128 + d];
  }
  int rg = tx >> 4, cg = tx & 15;
  float acc[4][4] = {};
  const float* Wh = W + head * 16384 + e0;
  for (int kk = 0; kk < 128; kk += 64) {
    __syncthreads();
#pragma unroll
    for (int t = 0; t < 16; t++) {
      int idx = t * 256 + tx, k = idx >> 6, j = idx & 63;
      wt[k * 68 + j] = Wh[(kk + k) * 128 + j];
    }
    __syncthreads();
    const float* hrow = &hs[(rg * 4) * 132 + kk];
#pragma unroll 4
    for (int d4 = 0; d4 < 64; d4 += 4) {
      float4 a[4];
      a[0] = *(const float4*)&hrow[d4];
      a[1] = *(const float4*)&hrow[132 + d4];
      a[2] = *(const float4*)&hrow[264 + d4];
      a[3] = *(const float4*)&hrow[396 + d4];
      float4 w0 = *(const float4*)&wt[(d4 + 0) * 68 + cg * 4];
      float4 w1v = *(const float4*)&wt[(d4 + 1) * 68 + cg * 4];
      float4 w2v = *(const float4*)&wt[(d4 + 2) * 68 + cg * 4];
      float4 w3v = *(const float4*)&wt[(d4 + 3) * 68 + cg * 4];
#pragma unroll
      for (int ri = 0; ri < 4; ri++) {
        acc[ri][0] = fmaf(a[ri].x, w0.x, acc[ri][0]);
        acc[ri][1] = fmaf(a[ri].x, w0.y, acc[ri][1]);
        acc[ri][2] = fmaf(a[ri].x, w0.z, acc[ri][2]);
        acc[ri][3] = fmaf(a[ri].x, w0.w, acc[ri][3]);
        acc[ri][0] = fmaf(a[ri].y, w1v.x, acc[ri][0]);
        acc[ri][1] = fmaf(a[ri].y, w1v.y, acc[ri][1]);
        acc[ri][2] = fmaf(a[ri].y, w1v.z, acc[ri][2]);
        acc[ri][3] = fmaf(a[ri].y, w1v.w, acc[ri][3]);
        acc[ri][0] = fmaf(a[ri].z, w2v.x, acc[ri][0]);
        acc[ri][1] = fmaf(a[ri].z, w2v.y, acc[ri][1]);
        acc[ri][2] = fmaf(a[ri].z, w2v.z, acc[ri][2]);
        acc[ri][3] = fmaf(a[ri].z, w2v.w, acc[ri][3]);
        acc[ri][0] = fmaf(a[ri].w, w3v.x, acc[ri][0]);
        acc[ri][1] = fmaf(a[ri].w, w3v.y, acc[ri][1]);
        acc[ri][2] = fmaf(a[ri].w, w3v.z, acc[ri][2]);
        acc[ri][3] = fmaf(a[ri].w, w3v.w, acc[ri][3]);
      }
    }
  }
#pragma unroll
  for (int ri = 0; ri < 4; ri++) {
    int grow = r0 + rg * 4 + ri;
    int eb = e0 + cg * 4;
    float v0 = acc[ri][0] + Bb[head * 128 + eb + 0];
    float v1 = acc[ri][1] + Bb[head * 128 + eb + 1];
    float v2 = acc[ri][2] + Bb[head * 128 + eb + 2];
    float v3 = acc[ri][3] + Bb[head * 128 + eb + 3];
    uint2 st = make_uint2(pack2(v0, v1), pack2(v2, v3));
    *(uint2*)&O[(head * 1024 + grow) * 128 + eb] = st;
  }
}

// ---------------- Kernel 3: attention, flash partials, bf16 LDS ------------------
#define SWZ(row, oct) ((row) * 136 + (((oct) ^ (((row) >> 1) & 7)) << 3))
__global__ __launch_bounds__(256) void k_attn() {
  __shared__ u16 Ks[64 * 136];
  __shared__ u16 Qs[64 * 136];
  __shared__ u16 Vs[64 * 136];
  __shared__ float Ss[64 * 68];
  int b = blockIdx.x, tx = threadIdx.x;
  int jc = b & 3, it = (b >> 2) & 7, hn = b >> 5;
  int i0 = it * 64;
  const u16* Kp = g_K + hn * 65536;
  const u16* Qp = g_Q + hn * 65536;
  const u16* Vp = g_V + hn * 65536;
#pragma unroll
  for (int t = 0; t < 4; t++) {
    int idx = t * 256 + tx, row = idx >> 4, oct = idx & 15;
    *(uint4*)&Ks[SWZ(row, oct)] = *(const uint4*)&Kp[(i0 + row) * 128 + oct * 8];
  }
  int rg = tx >> 4, cg = tx & 15;
  float o[4][8];
  float m_[4], l_[4];
#pragma unroll
  for (int i = 0; i < 4; i++) {
    m_[i] = -1e30f; l_[i] = 0.0f;
#pragma unroll
    for (int j = 0; j < 8; j++) o[i][j] = 0.0f;
  }
  for (int jt = 0; jt < 2; jt++) {
    int j0 = jc * 128 + jt * 64;
    __syncthreads();
#pragma unroll
    for (int t = 0; t < 4; t++) {
      int idx = t * 256 + tx, row = idx >> 4, oct = idx & 15;
      *(uint4*)&Qs[SWZ(row, oct)] = *(const uint4*)&Qp[(j0 + row) * 128 + oct * 8];
      *(uint4*)&Vs[SWZ(row, oct)] = *(const uint4*)&Vp[(j0 + row) * 128 + oct * 8];
    }
    __syncthreads();
    float s[4][4] = {};
    for (int oct = 0; oct < 16; oct++) {
      float kf[4][8], qf[4][8];
#pragma unroll
      for (int ri = 0; ri < 4; ri++) {
        uint4 kv = *(const uint4*)&Ks[SWZ(rg * 4 + ri, oct)];
        kf[ri][0] = lo16(kv.x); kf[ri][1] = hi16(kv.x);
        kf[ri][2] = lo16(kv.y); kf[ri][3] = hi16(kv.y);
        kf[ri][4] = lo16(kv.z); kf[ri][5] = hi16(kv.z);
        kf[ri][6] = lo16(kv.w); kf[ri][7] = hi16(kv.w);
      }
#pragma unroll
      for (int cj = 0; cj < 4; cj++) {
        uint4 qv = *(const uint4*)&Qs[SWZ(cg + 16 * cj, oct)];
        qf[cj][0] = lo16(qv.x); qf[cj][1] = hi16(qv.x);
        qf[cj][2] = lo16(qv.y); qf[cj][3] = hi16(qv.y);
        qf[cj][4] = lo16(qv.z); qf[cj][5] = hi16(qv.z);
        qf[cj][6] = lo16(qv.w); qf[cj][7] = hi16(qv.w);
      }
#pragma unroll
      for (int ri = 0; ri < 4; ri++)
#pragma unroll
        for (int cj = 0; cj < 4; cj++)
#pragma unroll
          for (int e = 0; e < 8; e++)
            s[ri][cj] = fmaf(kf[ri][e], qf[cj][e], s[ri][cj]);
    }
#pragma unroll
    for (int ri = 0; ri < 4; ri++) {
      float tm = -1e30f;
#pragma unroll
      for (int cj = 0; cj < 4; cj++) {
        float v = s[ri][cj];
        v = fmaxf(v, 0.2f * v);
        s[ri][cj] = v;
        tm = fmaxf(tm, v);
      }
      tm = fmaxf(tm, __shfl_xor(tm, 1)); tm = fmaxf(tm, __shfl_xor(tm, 2));
      tm = fmaxf(tm, __shfl_xor(tm, 4)); tm = fmaxf(tm, __shfl_xor(tm, 8));
      float mn = fmaxf(m_[ri], tm);
      float alpha = __expf(m_[ri] - mn);
      m_[ri] = mn;
      float p0 = __expf(s[ri][0] - mn), p1 = __expf(s[ri][1] - mn);
      float p2 = __expf(s[ri][2] - mn), p3 = __expf(s[ri][3] - mn);
      float ps = p0 + p1 + p2 + p3;
      ps += __shfl_xor(ps, 1); ps += __shfl_xor(ps, 2);
      ps += __shfl_xor(ps, 4); ps += __shfl_xor(ps, 8);
      l_[ri] = l_[ri] * alpha + ps;
      int row = rg * 4 + ri;
      Ss[row * 68 + cg +  0] = p0;
      Ss[row * 68 + cg + 16] = p1;
      Ss[row * 68 + cg + 32] = p2;
      Ss[row * 68 + cg + 48] = p3;
#pragma unroll
      for (int c = 0; c < 8; c++) o[ri][c] *= alpha;
    }
    __syncthreads();
    for (int j4 = 0; j4 < 64; j4 += 4) {
      float pv[4][4];
#pragma unroll
      for (int ri = 0; ri < 4; ri++)
        *(float4*)pv[ri] = *(const float4*)&Ss[(rg * 4 + ri) * 68 + j4];
#pragma unroll
      for (int jj = 0; jj < 4; jj++) {
        uint4 vv = *(const uint4*)&Vs[SWZ(j4 + jj, cg)];
        float vf0 = lo16(vv.x), vf1 = hi16(vv.x), vf2 = lo16(vv.y), vf3 = hi16(vv.y);
        float vf4 = lo16(vv.z), vf5 = hi16(vv.z), vf6 = lo16(vv.w), vf7 = hi16(vv.w);
#pragma unroll
        for (int ri = 0; ri < 4; ri++) {
          float p = pv[ri][jj];
          o[ri][0] = fmaf(p, vf0, o[ri][0]); o[ri][1] = fmaf(p, vf1, o[ri][1]);
          o[ri][2] = fmaf(p, vf2, o[ri][2]); o[ri][3] = fmaf(p, vf3, o[ri][3]);
          o[ri][4] = fmaf(p, vf4, o[ri][4]); o[ri][5] = fmaf(p, vf5, o[ri][5]);
          o[ri][6] = fmaf(p, vf6, o[ri][6]); o[ri][7] = fmaf(p, vf7, o[ri][7]);
        }
      }
    }
  }
#pragma unroll
  for (int ri = 0; ri < 4; ri++) {
    int row = rg * 4 + ri;
    float4 a = make_float4(o[ri][0], o[ri][1], o[ri][2], o[ri][3]);
    float4 c = make_float4(o[ri][4], o[ri][5], o[ri][6], o[ri][7]);
    *(float4*)&g_Op[(b * 64 + row) * 128 + cg * 8] = a;
    *(float4*)&g_Op[(b * 64 + row) * 128 + cg * 8 + 4] = c;
    if (cg == 0) {
      g_ml[(b * 64 + row) * 2 + 0] = m_[ri];
      g_ml[(b * 64 + row) * 2 + 1] = l_[ri];
    }
  }
}

// ---------------- Kernel 3b: merge 4 j-chunk partials -> g_att (bf16) ------------
__global__ void k_amerge() {
  int b = blockIdx.x, tx = threadIdx.x;
  int hn = b >> 5, ig = b & 31;
  int row = ig * 16 + (tx >> 4);
  int c8 = (tx & 15) * 8;
  int it = row >> 6, lr = row & 63;
  float mc[4], lc[4];
  float4 oa[4], ob[4];
#pragma unroll
  for (int c = 0; c < 4; c++) {
    int bp = hn * 32 + it * 4 + c;
    float2 ml = *(const float2*)&g_ml[(bp * 64 + lr) * 2];
    mc[c] = ml.x; lc[c] = ml.y;
    oa[c] = *(const float4*)&g_Op[(bp * 64 + lr) * 128 + c8];
    ob[c] = *(const float4*)&g_Op[(bp * 64 + lr) * 128 + c8 + 4];
  }
  float ms = fmaxf(fmaxf(mc[0], mc[1]), fmaxf(mc[2], mc[3]));
  float lsum = 0.0f;
  float ra[8] = {};
#pragma unroll
  for (int c = 0; c < 4; c++) {
    float w = __expf(mc[c] - ms);
    lsum += w * lc[c];
    ra[0] = fmaf(w, oa[c].x, ra[0]); ra[1] = fmaf(w, oa[c].y, ra[1]);
    ra[2] = fmaf(w, oa[c].z, ra[2]); ra[3] = fmaf(w, oa[c].w, ra[3]);
    ra[4] = fmaf(w, ob[c].x, ra[4]); ra[5] = fmaf(w, ob[c].y, ra[5]);
    ra[6] = fmaf(w, ob[c].z, ra[6]); ra[7] = fmaf(w, ob[c].w, ra[7]);
  }
  float inv = 1.0f / lsum;
  u16 pk[8];
#pragma unroll
  for (int e = 0; e < 8; e++) {
    float v = ra[e] * inv;
    v = fmaxf(v, 0.2f * v);
    pk[e] = f2b(v);
  }
  int h = hn >> 1, n = hn & 1;
  uint4 st;
  st.x = (u32)pk[0] | ((u32)pk[1] << 16);
  st.y = (u32)pk[2] | ((u32)pk[3] << 16);
  st.z = (u32)pk[4] | ((u32)pk[5] << 16);
  st.w = (u32)pk[6] | ((u32)pk[7] << 16);
  *(uint4*)&g_att[(n * 512 + row) * 1024 + h * 128 + c8] = st;
}

// ---------------- Kernel 4a: att@fv_w1 partials (4 rows x K-half per block) ------
__global__ void k_fv1(const float* __restrict__ w1) {
  __shared__ float atts[4 * 512];
  __shared__ float red[8 * 512];
  int b = blockIdx.x, tx = threadIdx.x;
  int row0 = (b >> 1) * 4, kh = b & 1, k0 = kh * 512;
#pragma unroll
  for (int j = 0; j < 8; j++) {
    int idx = j * 256 + tx, r = idx >> 9, c = idx & 511;
    atts[r * 512 + c] = lo16((u32)g_att[(row0 + r) * 1024 + k0 + c]);
  }
  __syncthreads();
  int ks = tx >> 5, eg = tx & 31;
  float acc[4][4] = {};
  int kbase = k0 + ks * 64;
#pragma unroll 4
  for (int i = 0; i < 64; i++) {
    int k = kbase + i;
    float4 w4 = *(const float4*)&w1[k * 128 + eg * 4];
    int kl = ks * 64 + i;
    float a0 = atts[kl], a1 = atts[512 + kl], a2 = atts[1024 + kl], a3 = atts[1536 + kl];
    acc[0][0] = fmaf(a0, w4.x, acc[0][0]); acc[0][1] = fmaf(a0, w4.y, acc[0][1]);
    acc[0][2] = fmaf(a0, w4.z, acc[0][2]); acc[0][3] = fmaf(a0, w4.w, acc[0][3]);
    acc[1][0] = fmaf(a1, w4.x, acc[1][0]); acc[1][1] = fmaf(a1, w4.y, acc[1][1]);
    acc[1][2] = fmaf(a1, w4.z, acc[1][2]); acc[1][3] = fmaf(a1, w4.w, acc[1][3]);
    acc[2][0] = fmaf(a2, w4.x, acc[2][0]); acc[2][1] = fmaf(a2, w4.y, acc[2][1]);
    acc[2][2] = fmaf(a2, w4.z, acc[2][2]); acc[2][3] = fmaf(a2, w4.w, acc[2][3]);
    acc[3][0] = fmaf(a3, w4.x, acc[3][0]); acc[3][1] = fmaf(a3, w4.y, acc[3][1]);
    acc[3][2] = fmaf(a3, w4.z, acc[3][2]); acc[3][3] = fmaf(a3, w4.w, acc[3][3]);
  }
#pragma unroll
  for (int r = 0; r < 4; r++)
    *(float4*)&red[ks * 512 + r * 128 + eg * 4] = *(float4*)acc[r];
  __syncthreads();
#pragma unroll
  for (int jo = 0; jo < 2; jo++) {
    int o = jo * 256 + tx;
    float s = 0.0f;
#pragma unroll
    for (int k8 = 0; k8 < 8; k8++) s += red[k8 * 512 + o];
    int r = o >> 7, e = o & 127;
    g_part[kh * 131072 + (row0 + r) * 128 + e] = s;
  }
}

// ---------------- Kernel 4b: bias+relu, @fv_w2, residual, A/B projections --------
__global__ void k_fv2(const float* __restrict__ b1, const float* __restrict__ w2,
                      const float* __restrict__ b2, const float* __restrict__ few1,
                      const float* __restrict__ feb1, float* __restrict__ x2out) {
  __shared__ float hids[2 * 128];
  __shared__ float x2s[2 * 128];
  __shared__ float red[8 * 256];
  int b = blockIdx.x, tx = threadIdx.x;
  int row0 = b * 2;
  {
    int r = tx >> 7, e = tx & 127;
    int gi = (row0 + r) * 128 + e;
    float s = g_part[gi] + g_part[131072 + gi] + b1[e];
    hids[tx] = fmaxf(s, 0.0f);
  }
  __syncthreads();
  int ks = tx >> 5, eg = tx & 31;
  // hid @ w2
  {
    float acc[2][4] = {};
#pragma unroll 4
    for (int i = 0; i < 16; i++) {
      int k = ks * 16 + i;
      float4 w4 = *(const float4*)&w2[k * 128 + eg * 4];
      float a0 = hids[k], a1 = hids[128 + k];
      acc[0][0] = fmaf(a0, w4.x, acc[0][0]); acc[0][1] = fmaf(a0, w4.y, acc[0][1]);
      acc[0][2] = fmaf(a0, w4.z, acc[0][2]); acc[0][3] = fmaf(a0, w4.w, acc[0][3]);
      acc[1][0] = fmaf(a1, w4.x, acc[1][0]); acc[1][1] = fmaf(a1, w4.y, acc[1][1]);
      acc[1][2] = fmaf(a1, w4.z, acc[1][2]); acc[1][3] = fmaf(a1, w4.w, acc[1][3]);
    }
#pragma unroll
    for (int r = 0; r < 2; r++)
      *(float4*)&red[ks * 256 + r * 128 + eg * 4] = *(float4*)acc[r];
  }
  __syncthreads();
  {
    float s = 0.0f;
#pragma unroll
    for (int k8 = 0; k8 < 8; k8++) s += red[k8 * 256 + tx];
    int r = tx >> 7, e = tx & 127;
    int gi = (row0 + r) * 128 + e;
    float c = s + b2[e] + g_h[gi];
    x2s[tx] = c;
    x2out[gi] = c;
  }
  __syncthreads();
  // A = x2 @ few1[:128] + feb1 ; B = x2 @ few1[128:]
  float aA[2][4] = {}, aB[2][4] = {};
#pragma unroll 4
  for (int i = 0; i < 16; i++) {
    int k = ks * 16 + i;
    float4 wa = *(const float4*)&few1[k * 128 + eg * 4];
    float4 wb = *(const float4*)&few1[(128 + k) * 128 + eg * 4];
    float a0 = x2s[k], a1 = x2s[128 + k];
    aA[0][0] = fmaf(a0, wa.x, aA[0][0]); aA[0][1] = fmaf(a0, wa.y, aA[0][1]);
    aA[0][2] = fmaf(a0, wa.z, aA[0][2]); aA[0][3] = fmaf(a0, wa.w, aA[0][3]);
    aA[1][0] = fmaf(a1, wa.x, aA[1][0]); aA[1][1] = fmaf(a1, wa.y, aA[1][1]);
    aA[1][2] = fmaf(a1, wa.z, aA[1][2]); aA[1][3] = fmaf(a1, wa.w, aA[1][3]);
    aB[0][0] = fmaf(a0, wb.x, aB[0][0]); aB[0][1] = fmaf(a0, wb.y, aB[0][1]);
    aB[0][2] = fmaf(a0, wb.z, aB[0][2]); aB[0][3] = fmaf(a0, wb.w, aB[0][3]);
    aB[1][0] = fmaf(a1, wb.x, aB[1][0]); aB[1][1] = fmaf(a1, wb.y, aB[1][1]);
    aB[1][2] = fmaf(a1, wb.z, aB[1][2]); aB[1][3] = fmaf(a1, wb.w, aB[1][3]);
  }
  __syncthreads();  // red reads done before overwrite
#pragma unroll
  for (int r = 0; r < 2; r++)
    *(float4*)&red[ks * 256 + r * 128 + eg * 4] = *(float4*)aA[r];
  __syncthreads();
  {
    float s = 0.0f;
#pragma unroll
    for (int k8 = 0; k8 < 8; k8++) s += red[k8 * 256 + tx];
    int r = tx >> 7, e = tx & 127;
    g_A[(row0 + r) * 128 + e] = s + feb1[e];
  }
  __syncthreads();
#pragma unroll
  for (int r = 0; r < 2; r++)
    *(float4*)&red[ks * 256 + r * 128 + eg * 4] = *(float4*)aB[r];
  __syncthreads();
  {
    float s = 0.0f;
#pragma unroll
    for (int k8 = 0; k8 < 8; k8++) s += red[k8 * 256 + tx];
    int r = tx >> 7, e = tx & 127;
    g_Bm[(row0 + r) * 128 + e] = s;
  }
}

// ---------------- Kernel 5: pairwise edge FFN (A_i + B_j factorized) -------------
__global__ void k_edge(const float* __restrict__ few2, const float* __restrict__ feb2,
                       float* __restrict__ edge) {
  __shared__ float As[4 * 128];
  __shared__ float w2s[128];
  int b = blockIdx.x, tx = threadIdx.x;
  int n = b >> 8, rest = b & 255, ig = rest >> 1, jh = rest & 1;
  int i0 = ig * 4;
  if (tx < 128) w2s[tx] = few2[tx];
  As[tx] = g_A[(n * 512 + i0) * 128 + tx];
  As[tx + 256] = g_A[(n * 512 + i0) * 128 + tx + 256];
  float eb2 = feb2[0];
  __syncthreads();
  int j = jh * 256 + tx;
  const float* B0 = &g_Bm[(n * 512 + j) * 128];
  float acc[4] = {};
#pragma unroll 4
  for (int dc = 0; dc < 32; dc++) {
    float4 bv = *(const float4*)&B0[dc * 4];
    float4 w4 = *(const float4*)&w2s[dc * 4];
#pragma unroll
    for (int i = 0; i < 4; i++) {
      float4 a4 = *(const float4*)&As[i * 128 + dc * 4];
      acc[i] = fmaf(fmaxf(a4.x + bv.x, 0.0f), w4.x, acc[i]);
      acc[i] = fmaf(fmaxf(a4.y + bv.y, 0.0f), w4.y, acc[i]);
      acc[i] = fmaf(fmaxf(a4.z + bv.z, 0.0f), w4.z, acc[i]);
      acc[i] = fmaf(fmaxf(a4.w + bv.w, 0.0f), w4.w, acc[i]);
    }
  }
  const float scale = 1.0f / 512.0f;
#pragma unroll
  for (int i = 0; i < 4; i++)
    edge[(n * 512 + i0 + i) * 512 + j] = (acc[i] + eb2) * scale;
}

extern "C" void kernel_launch(void* const* d_in, const int* in_sizes, int n_in,
                              void* d_out, int out_size, void* d_ws, size_t ws_size,
                              hipStream_t stream) {
  (void)in_sizes; (void)n_in; (void)out_size; (void)d_ws; (void)ws_size;
  const float* x     = (const float*)d_in[0];
  const float* fn_w1 = (const float*)d_in[1];
  const float* fn_b1 = (const float*)d_in[2];
  const float* fn_w2 = (const float*)d_in[3];
  const float* fn_b2 = (const float*)d_in[4];
  const float* wk    = (const float*)d_in[5];
  const float* bk    = (const float*)d_in[6];
  const float* wq    = (const float*)d_in[7];
  const float* bq    = (const float*)d_in[8];
  const float* wv    = (const float*)d_in[9];
  const float* bv    = (const float*)d_in[10];
  const float* fv_w1 = (const float*)d_in[11];
  const float* fv_b1 = (const float*)d_in[12];
  const float* fv_w2 = (const float*)d_in[13];
  const float* fv_b2 = (const float*)d_in[14];
  const float* fe_w1 = (const float*)d_in[15];
  const float* fe_b1 = (const float*)d_in[16];
  const float* fe_w2 = (const float*)d_in[17];
  const float* fe_b2 = (const float*)d_in[18];

  float* x2out = (float*)d_out;      // [0, 131072) floats
  float* edge  = x2out + 131072;     // [131072, 655360) floats

  k_fnode<<<512, 256, 0, stream>>>(x, fn_w1, fn_b1, fn_w2, fn_b2);
  k_kqv<<<768, 256, 0, stream>>>(wk, bk, wq, bq, wv, bv);
  k_attn<<<512, 256, 0, stream>>>();
  k_amerge<<<512, 256, 0, stream>>>();
  k_fv1<<<512, 256, 0, stream>>>(fv_w1);
  k_fv2<<<512, 256, 0, stream>>>(fv_b1, fv_w2, fv_b2, fe_w1, fe_b1, x2out);
  k_edge<<<512, 256, 0, stream>>>(fe_w2, fe_b2, edge);
}

// Round 8
// 162.559 us; speedup vs baseline: 2.5401x; 1.1679x over previous
//
#include <hip/hip_runtime.h>

typedef unsigned short u16;
typedef unsigned int u32;
typedef __attribute__((ext_vector_type(8))) short short8;
typedef __attribute__((ext_vector_type(4))) float f32x4;

__device__ __forceinline__ u16 f2b(float f) {
  union { float f; u32 i; } v; v.f = f;
  u32 i = v.i;
  return (u16)((i + 0x7FFFu + ((i >> 16) & 1u)) >> 16);
}
__device__ __forceinline__ float lo16(u32 x) { union { u32 i; float f; } v; v.i = x << 16; return v.f; }
__device__ __forceinline__ float hi16(u32 x) { union { u32 i; float f; } v; v.i = x & 0xffff0000u; return v.f; }
__device__ __forceinline__ u32 pack2(float a, float b) { return (u32)f2b(a) | ((u32)f2b(b) << 16); }

// Sizes: N=2, M=512, D_IN=64, D=128, H=8. Rows = N*M = 1024. hn = h*2+n in [0,16).
__device__ __align__(16) float g_h[1024 * 128];
__device__ __align__(16) u16   g_K[16 * 512 * 128];   // bf16 [hn][m][d]
__device__ __align__(16) u16   g_Q[16 * 512 * 128];
__device__ __align__(16) u16   g_V[16 * 512 * 128];
__device__ __align__(16) float g_Op[512 * 64 * 128];  // flash partials per (hn,it,jc) block
__device__ __align__(16) float g_ml[512 * 64 * 2];
__device__ __align__(16) u16   g_att[1024 * 1024];    // bf16 concat [n*512+m][h*128+e]
__device__ __align__(16) float g_part[2 * 1024 * 128]; // fv1 K-half partials
__device__ __align__(16) float g_A[1024 * 128];
__device__ __align__(16) float g_Bm[1024 * 128];

// ---------------- Kernel 1: f_node, 2 rows/block, float4 weights, K-split --------
__global__ void k_fnode(const float* __restrict__ x, const float* __restrict__ w1,
                        const float* __restrict__ b1, const float* __restrict__ w2,
                        const float* __restrict__ b2) {
  __shared__ float xr[2 * 64];
  __shared__ float hids[2 * 256];
  __shared__ float red[2048];
  int tx = threadIdx.x;
  int row0 = blockIdx.x * 2;
  if (tx < 128) {
    int r = tx >> 6, k = tx & 63;
    xr[tx] = x[(row0 + r) * 64 + k] + sinf((float)k * (5.0f / 63.0f));
  }
  __syncthreads();
  {
    int ks = tx >> 6, cg = tx & 63;
    float acc[2][4] = {};
#pragma unroll 4
    for (int i = 0; i < 16; i++) {
      int k = ks * 16 + i;
      float4 w4 = *(const float4*)&w1[k * 256 + cg * 4];
      float a0 = xr[k], a1 = xr[64 + k];
      acc[0][0] = fmaf(a0, w4.x, acc[0][0]); acc[0][1] = fmaf(a0, w4.y, acc[0][1]);
      acc[0][2] = fmaf(a0, w4.z, acc[0][2]); acc[0][3] = fmaf(a0, w4.w, acc[0][3]);
      acc[1][0] = fmaf(a1, w4.x, acc[1][0]); acc[1][1] = fmaf(a1, w4.y, acc[1][1]);
      acc[1][2] = fmaf(a1, w4.z, acc[1][2]); acc[1][3] = fmaf(a1, w4.w, acc[1][3]);
    }
#pragma unroll
    for (int r = 0; r < 2; r++)
      *(float4*)&red[ks * 512 + r * 256 + cg * 4] = *(float4*)acc[r];
  }
  __syncthreads();
#pragma unroll
  for (int jo = 0; jo < 2; jo++) {
    int o = jo * 256 + tx;
    float s = red[o] + red[512 + o] + red[1024 + o] + red[1536 + o];
    hids[o] = fmaxf(s + b1[o & 255], 0.0f);
  }
  __syncthreads();
  {
    int ks = tx >> 5, eg = tx & 31;
    float acc[2][4] = {};
#pragma unroll 4
    for (int i = 0; i < 32; i++) {
      int k = ks * 32 + i;
      float4 w4 = *(const float4*)&w2[k * 128 + eg * 4];
      float a0 = hids[k], a1 = hids[256 + k];
      acc[0][0] = fmaf(a0, w4.x, acc[0][0]); acc[0][1] = fmaf(a0, w4.y, acc[0][1]);
      acc[0][2] = fmaf(a0, w4.z, acc[0][2]); acc[0][3] = fmaf(a0, w4.w, acc[0][3]);
      acc[1][0] = fmaf(a1, w4.x, acc[1][0]); acc[1][1] = fmaf(a1, w4.y, acc[1][1]);
      acc[1][2] = fmaf(a1, w4.z, acc[1][2]); acc[1][3] = fmaf(a1, w4.w, acc[1][3]);
    }
    __syncthreads();
#pragma unroll
    for (int r = 0; r < 2; r++)
      *(float4*)&red[ks * 256 + r * 128 + eg * 4] = *(float4*)acc[r];
  }
  __syncthreads();
  {
    float s = 0.0f;
#pragma unroll
    for (int ks = 0; ks < 8; ks++) s += red[ks * 256 + tx];
    int r = tx >> 7, e = tx & 127;
    g_h[(row0 + r) * 128 + e] = s + b2[e];
  }
}

// ---------------- Kernel 2: K/Q/V projections, bf16 out, vector LDS --------------
__global__ void k_kqv(const float* __restrict__ wk, const float* __restrict__ bk,
                      const float* __restrict__ wq, const float* __restrict__ bq,
                      const float* __restrict__ wv, const float* __restrict__ bv) {
  int b = blockIdx.x, tx = threadIdx.x;
  int ct = b % 48, rt = b / 48;
  int c0 = ct * 64;
  int proj = c0 >> 10, rem = c0 & 1023, head = rem >> 7, e0 = rem & 127;
  const float* W  = (proj == 0) ? wk : (proj == 1) ? wq : wv;
  const float* Bb = (proj == 0) ? bk : (proj == 1) ? bq : bv;
  u16* O = (proj == 0) ? g_K : (proj == 1) ? g_Q : g_V;
  __shared__ float hs[64 * 132];
  __shared__ float wt[64 * 68];
  int r0 = rt * 64;
#pragma unroll
  for (int t = 0; t < 32; t++) {
    int idx = t * 256 + tx, r = idx >> 7, d = idx & 127;
    hs[r * 132 + d] = g_h[(r0 + r) * 128 + d];
  }
  int rg = tx >> 4, cg = tx & 15;
  float acc[4][4] = {};
  const float* Wh = W + head * 16384 + e0;
  for (int kk = 0; kk < 128; kk += 64) {
    __syncthreads();
#pragma unroll
    for (int t = 0; t < 16; t++) {
      int idx = t * 256 + tx, k = idx >> 6, j = idx & 63;
      wt[k * 68 + j] = Wh[(kk + k) * 128 + j];
    }
    __syncthreads();
    const float* hrow = &hs[(rg * 4) * 132 + kk];
#pragma unroll 4
    for (int d4 = 0; d4 < 64; d4 += 4) {
      float4 a[4];
      a[0] = *(const float4*)&hrow[d4];
      a[1] = *(const float4*)&hrow[132 + d4];
      a[2] = *(const float4*)&hrow[264 + d4];
      a[3] = *(const float4*)&hrow[396 + d4];
      float4 w0 = *(const float4*)&wt[(d4 + 0) * 68 + cg * 4];
      float4 w1v = *(const float4*)&wt[(d4 + 1) * 68 + cg * 4];
      float4 w2v = *(const float4*)&wt[(d4 + 2) * 68 + cg * 4];
      float4 w3v = *(const float4*)&wt[(d4 + 3) * 68 + cg * 4];
#pragma unroll
      for (int ri = 0; ri < 4; ri++) {
        acc[ri][0] = fmaf(a[ri].x, w0.x, acc[ri][0]);
        acc[ri][1] = fmaf(a[ri].x, w0.y, acc[ri][1]);
        acc[ri][2] = fmaf(a[ri].x, w0.z, acc[ri][2]);
        acc[ri][3] = fmaf(a[ri].x, w0.w, acc[ri][3]);
        acc[ri][0] = fmaf(a[ri].y, w1v.x, acc[ri][0]);
        acc[ri][1] = fmaf(a[ri].y, w1v.y, acc[ri][1]);
        acc[ri][2] = fmaf(a[ri].y, w1v.z, acc[ri][2]);
        acc[ri][3] = fmaf(a[ri].y, w1v.w, acc[ri][3]);
        acc[ri][0] = fmaf(a[ri].z, w2v.x, acc[ri][0]);
        acc[ri][1] = fmaf(a[ri].z, w2v.y, acc[ri][1]);
        acc[ri][2] = fmaf(a[ri].z, w2v.z, acc[ri][2]);
        acc[ri][3] = fmaf(a[ri].z, w2v.w, acc[ri][3]);
        acc[ri][0] = fmaf(a[ri].w, w3v.x, acc[ri][0]);
        acc[ri][1] = fmaf(a[ri].w, w3v.y, acc[ri][1]);
        acc[ri][2] = fmaf(a[ri].w, w3v.z, acc[ri][2]);
        acc[ri][3] = fmaf(a[ri].w, w3v.w, acc[ri][3]);
      }
    }
  }
#pragma unroll
  for (int ri = 0; ri < 4; ri++) {
    int grow = r0 + rg * 4 + ri;
    int eb = e0 + cg * 4;
    float v0 = acc[ri][0] + Bb[head * 128 + eb + 0];
    float v1 = acc[ri][1] + Bb[head * 128 + eb + 1];
    float v2 = acc[ri][2] + Bb[head * 128 + eb + 2];
    float v3 = acc[ri][3] + Bb[head * 128 + eb + 3];
    uint2 st = make_uint2(pack2(v0, v1), pack2(v2, v3));
    *(uint2*)&O[(head * 1024 + grow) * 128 + eb] = st;
  }
}

// ---------------- Kernel 3: attention via MFMA 16x16x32 bf16 ---------------------
// b = hn*32 + it*4 + jc. i-tile 64 (4 waves x 16 rows), j-chunk 128 (2 j-tiles of 64).
// S^T = Q·K^T (C/D: col=lane&15=i, row=quad*4+reg=j); softmax over j; P via LDS
// round-trip to A-layout; O += P·V with V^T staged in LDS.
__global__ __launch_bounds__(256) void k_attn() {
  __shared__ u16 Ks[64 * 136];     // [i-local][d], stride 272B (17 x 16B)
  __shared__ u16 Qs[64 * 136];     // [j-local][d]
  __shared__ u16 Vt[128 * 72];     // [e][j-local], stride 144B (9 x 16B)
  __shared__ u16 Pw[4 * 16 * 72];  // per-wave P[i-local16][j-local64]
  __shared__ float alphas[4 * 16];
  int b = blockIdx.x, tx = threadIdx.x;
  int jc = b & 3, it = (b >> 2) & 7, hn = b >> 5;
  int i0 = it * 64;
  const u16* Kp = g_K + hn * 65536;
  const u16* Qp = g_Q + hn * 65536;
  const u16* Vp = g_V + hn * 65536;
#pragma unroll
  for (int t = 0; t < 4; t++) {
    int idx = t * 256 + tx, row = idx >> 4, oct = idx & 15;
    *(uint4*)&Ks[row * 136 + oct * 8] = *(const uint4*)&Kp[(i0 + row) * 128 + oct * 8];
  }
  int lane = tx & 63, wv = tx >> 6;
  int cl = lane & 15, quad = lane >> 4;
  f32x4 zero = {0.0f, 0.0f, 0.0f, 0.0f};
  f32x4 o[8];
#pragma unroll
  for (int es = 0; es < 8; es++) o[es] = zero;
  float m_ = -1e30f, l_ = 0.0f;   // row-state for i = wv*16+cl (replicated over quads)

  for (int jt = 0; jt < 2; jt++) {
    int j0 = jc * 128 + jt * 64;
    __syncthreads();  // prior PV reads of Vt/Pw done (covers Ks staging at jt=0)
#pragma unroll
    for (int t = 0; t < 4; t++) {
      int idx = t * 256 + tx, row = idx >> 4, oct = idx & 15;
      *(uint4*)&Qs[row * 136 + oct * 8] = *(const uint4*)&Qp[(j0 + row) * 128 + oct * 8];
    }
    {  // stage V transposed: Vt[e][j-local]
      int jg = (tx & 15) * 4, e8 = (tx >> 4) * 8;
      uint4 r0 = *(const uint4*)&Vp[(j0 + jg + 0) * 128 + e8];
      uint4 r1 = *(const uint4*)&Vp[(j0 + jg + 1) * 128 + e8];
      uint4 r2 = *(const uint4*)&Vp[(j0 + jg + 2) * 128 + e8];
      uint4 r3 = *(const uint4*)&Vp[(j0 + jg + 3) * 128 + e8];
      const u32* p0 = (const u32*)&r0; const u32* p1 = (const u32*)&r1;
      const u32* p2 = (const u32*)&r2; const u32* p3 = (const u32*)&r3;
#pragma unroll
      for (int c = 0; c < 8; c++) {
        int w = c >> 1, sh = (c & 1) * 16;
        u32 lo = ((p0[w] >> sh) & 0xffffu) | (((p1[w] >> sh) & 0xffffu) << 16);
        u32 hi = ((p2[w] >> sh) & 0xffffu) | (((p3[w] >> sh) & 0xffffu) << 16);
        *(uint2*)&Vt[(e8 + c) * 72 + jg] = make_uint2(lo, hi);
      }
    }
    __syncthreads();
    // --- S^T: A = Q rows (m=j), B = K rows (n=i) ---
    short8 bK[4];
#pragma unroll
    for (int kk = 0; kk < 4; kk++)
      bK[kk] = *(const short8*)&Ks[(wv * 16 + cl) * 136 + kk * 32 + quad * 8];
    f32x4 st[4];
#pragma unroll
    for (int s = 0; s < 4; s++) {
      f32x4 acc = zero;
#pragma unroll
      for (int kk = 0; kk < 4; kk++) {
        short8 aQ = *(const short8*)&Qs[(s * 16 + cl) * 136 + kk * 32 + quad * 8];
        acc = __builtin_amdgcn_mfma_f32_16x16x32_bf16(aQ, bK[kk], acc, 0, 0, 0);
      }
      st[s] = acc;
    }
    // --- leaky + online softmax over j (lane-local 16 + quad reduce) ---
    float p[4][4];
    float tm = -1e30f;
#pragma unroll
    for (int s = 0; s < 4; s++)
#pragma unroll
      for (int r = 0; r < 4; r++) {
        float v = st[s][r];
        v = fmaxf(v, 0.2f * v);
        p[s][r] = v;
        tm = fmaxf(tm, v);
      }
    tm = fmaxf(tm, __shfl_xor(tm, 16));
    tm = fmaxf(tm, __shfl_xor(tm, 32));
    float mn = fmaxf(m_, tm);
    float alpha = __expf(m_ - mn);
    m_ = mn;
    float ps = 0.0f;
#pragma unroll
    for (int s = 0; s < 4; s++)
#pragma unroll
      for (int r = 0; r < 4; r++) {
        float e = __expf(p[s][r] - mn);
        p[s][r] = e;
        ps += e;
      }
    ps += __shfl_xor(ps, 16);
    ps += __shfl_xor(ps, 32);
    l_ = l_ * alpha + ps;
    // write P (bf16) to per-wave LDS in [i][j] layout
#pragma unroll
    for (int s = 0; s < 4; s++) {
      uint2 w2v = make_uint2(pack2(p[s][0], p[s][1]), pack2(p[s][2], p[s][3]));
      *(uint2*)&Pw[(wv * 16 + cl) * 72 + s * 16 + quad * 4] = w2v;
    }
    if (quad == 0) alphas[wv * 16 + cl] = alpha;
    __syncthreads();  // Pw + alphas visible
    // --- rescale O, then O += P·V ---
    f32x4 av = *(const f32x4*)&alphas[wv * 16 + quad * 4];  // alpha for i=quad*4+reg
#pragma unroll
    for (int es = 0; es < 8; es++) o[es] *= av;
    short8 aP[2];
#pragma unroll
    for (int k2 = 0; k2 < 2; k2++)
      aP[k2] = *(const short8*)&Pw[(wv * 16 + cl) * 72 + k2 * 32 + quad * 8];
#pragma unroll
    for (int es = 0; es < 8; es++) {
#pragma unroll
      for (int k2 = 0; k2 < 2; k2++) {
        short8 bV = *(const short8*)&Vt[(es * 16 + cl) * 72 + k2 * 32 + quad * 8];
        o[es] = __builtin_amdgcn_mfma_f32_16x16x32_bf16(aP[k2], bV, o[es], 0, 0, 0);
      }
    }
  }
  // epilogue: unnormalized partials + (m,l) for k_amerge
#pragma unroll
  for (int es = 0; es < 8; es++)
#pragma unroll
    for (int r = 0; r < 4; r++)
      g_Op[(b * 64 + wv * 16 + quad * 4 + r) * 128 + es * 16 + cl] = o[es][r];
  if (quad == 0) {
    g_ml[(b * 64 + wv * 16 + cl) * 2 + 0] = m_;
    g_ml[(b * 64 + wv * 16 + cl) * 2 + 1] = l_;
  }
}

// ---------------- Kernel 3b: merge 4 j-chunk partials -> g_att (bf16) ------------
__global__ void k_amerge() {
  int b = blockIdx.x, tx = threadIdx.x;
  int hn = b >> 5, ig = b & 31;
  int row = ig * 16 + (tx >> 4);
  int c8 = (tx & 15) * 8;
  int it = row >> 6, lr = row & 63;
  float mc[4], lc[4];
  float4 oa[4], ob[4];
#pragma unroll
  for (int c = 0; c < 4; c++) {
    int bp = hn * 32 + it * 4 + c;
    float2 ml = *(const float2*)&g_ml[(bp * 64 + lr) * 2];
    mc[c] = ml.x; lc[c] = ml.y;
    oa[c] = *(const float4*)&g_Op[(bp * 64 + lr) * 128 + c8];
    ob[c] = *(const float4*)&g_Op[(bp * 64 + lr) * 128 + c8 + 4];
  }
  float ms = fmaxf(fmaxf(mc[0], mc[1]), fmaxf(mc[2], mc[3]));
  float lsum = 0.0f;
  float ra[8] = {};
#pragma unroll
  for (int c = 0; c < 4; c++) {
    float w = __expf(mc[c] - ms);
    lsum += w * lc[c];
    ra[0] = fmaf(w, oa[c].x, ra[0]); ra[1] = fmaf(w, oa[c].y, ra[1]);
    ra[2] = fmaf(w, oa[c].z, ra[2]); ra[3] = fmaf(w, oa[c].w, ra[3]);
    ra[4] = fmaf(w, ob[c].x, ra[4]); ra[5] = fmaf(w, ob[c].y, ra[5]);
    ra[6] = fmaf(w, ob[c].z, ra[6]); ra[7] = fmaf(w, ob[c].w, ra[7]);
  }
  float inv = 1.0f / lsum;
  u16 pk[8];
#pragma unroll
  for (int e = 0; e < 8; e++) {
    float v = ra[e] * inv;
    v = fmaxf(v, 0.2f * v);
    pk[e] = f2b(v);
  }
  int h = hn >> 1, n = hn & 1;
  uint4 st;
  st.x = (u32)pk[0] | ((u32)pk[1] << 16);
  st.y = (u32)pk[2] | ((u32)pk[3] << 16);
  st.z = (u32)pk[4] | ((u32)pk[5] << 16);
  st.w = (u32)pk[6] | ((u32)pk[7] << 16);
  *(uint4*)&g_att[(n * 512 + row) * 1024 + h * 128 + c8] = st;
}

// ---------------- Kernel 4a: att@fv_w1 partials (4 rows x K-half per block) ------
__global__ void k_fv1(const float* __restrict__ w1) {
  __shared__ float atts[4 * 512];
  __shared__ float red[8 * 512];
  int b = blockIdx.x, tx = threadIdx.x;
  int row0 = (b >> 1) * 4, kh = b & 1, k0 = kh * 512;
#pragma unroll
  for (int j = 0; j < 8; j++) {
    int idx = j * 256 + tx, r = idx >> 9, c = idx & 511;
    atts[r * 512 + c] = lo16((u32)g_att[(row0 + r) * 1024 + k0 + c]);
  }
  __syncthreads();
  int ks = tx >> 5, eg = tx & 31;
  float acc[4][4] = {};
  int kbase = k0 + ks * 64;
#pragma unroll 4
  for (int i = 0; i < 64; i++) {
    int k = kbase + i;
    float4 w4 = *(const float4*)&w1[k * 128 + eg * 4];
    int kl = ks * 64 + i;
    float a0 = atts[kl], a1 = atts[512 + kl], a2 = atts[1024 + kl], a3 = atts[1536 + kl];
    acc[0][0] = fmaf(a0, w4.x, acc[0][0]); acc[0][1] = fmaf(a0, w4.y, acc[0][1]);
    acc[0][2] = fmaf(a0, w4.z, acc[0][2]); acc[0][3] = fmaf(a0, w4.w, acc[0][3]);
    acc[1][0] = fmaf(a1, w4.x, acc[1][0]); acc[1][1] = fmaf(a1, w4.y, acc[1][1]);
    acc[1][2] = fmaf(a1, w4.z, acc[1][2]); acc[1][3] = fmaf(a1, w4.w, acc[1][3]);
    acc[2][0] = fmaf(a2, w4.x, acc[2][0]); acc[2][1] = fmaf(a2, w4.y, acc[2][1]);
    acc[2][2] = fmaf(a2, w4.z, acc[2][2]); acc[2][3] = fmaf(a2, w4.w, acc[2][3]);
    acc[3][0] = fmaf(a3, w4.x, acc[3][0]); acc[3][1] = fmaf(a3, w4.y, acc[3][1]);
    acc[3][2] = fmaf(a3, w4.z, acc[3][2]); acc[3][3] = fmaf(a3, w4.w, acc[3][3]);
  }
#pragma unroll
  for (int r = 0; r < 4; r++)
    *(float4*)&red[ks * 512 + r * 128 + eg * 4] = *(float4*)acc[r];
  __syncthreads();
#pragma unroll
  for (int jo = 0; jo < 2; jo++) {
    int o = jo * 256 + tx;
    float s = 0.0f;
#pragma unroll
    for (int k8 = 0; k8 < 8; k8++) s += red[k8 * 512 + o];
    int r = o >> 7, e = o & 127;
    g_part[kh * 131072 + (row0 + r) * 128 + e] = s;
  }
}

// ---------------- Kernel 4b: bias+relu, @fv_w2, residual, A/B projections --------
__global__ void k_fv2(const float* __restrict__ b1, const float* __restrict__ w2,
                      const float* __restrict__ b2, const float* __restrict__ few1,
                      const float* __restrict__ feb1, float* __restrict__ x2out) {
  __shared__ float hids[2 * 128];
  __shared__ float x2s[2 * 128];
  __shared__ float red[8 * 256];
  int b = blockIdx.x, tx = threadIdx.x;
  int row0 = b * 2;
  {
    int r = tx >> 7, e = tx & 127;
    int gi = (row0 + r) * 128 + e;
    float s = g_part[gi] + g_part[131072 + gi] + b1[e];
    hids[tx] = fmaxf(s, 0.0f);
  }
  __syncthreads();
  int ks = tx >> 5, eg = tx & 31;
  {
    float acc[2][4] = {};
#pragma unroll 4
    for (int i = 0; i < 16; i++) {
      int k = ks * 16 + i;
      float4 w4 = *(const float4*)&w2[k * 128 + eg * 4];
      float a0 = hids[k], a1 = hids[128 + k];
      acc[0][0] = fmaf(a0, w4.x, acc[0][0]); acc[0][1] = fmaf(a0, w4.y, acc[0][1]);
      acc[0][2] = fmaf(a0, w4.z, acc[0][2]); acc[0][3] = fmaf(a0, w4.w, acc[0][3]);
      acc[1][0] = fmaf(a1, w4.x, acc[1][0]); acc[1][1] = fmaf(a1, w4.y, acc[1][1]);
      acc[1][2] = fmaf(a1, w4.z, acc[1][2]); acc[1][3] = fmaf(a1, w4.w, acc[1][3]);
    }
#pragma unroll
    for (int r = 0; r < 2; r++)
      *(float4*)&red[ks * 256 + r * 128 + eg * 4] = *(float4*)acc[r];
  }
  __syncthreads();
  {
    float s = 0.0f;
#pragma unroll
    for (int k8 = 0; k8 < 8; k8++) s += red[k8 * 256 + tx];
    int r = tx >> 7, e = tx & 127;
    int gi = (row0 + r) * 128 + e;
    float c = s + b2[e] + g_h[gi];
    x2s[tx] = c;
    x2out[gi] = c;
  }
  __syncthreads();
  float aA[2][4] = {}, aB[2][4] = {};
#pragma unroll 4
  for (int i = 0; i < 16; i++) {
    int k = ks * 16 + i;
    float4 wa = *(const float4*)&few1[k * 128 + eg * 4];
    float4 wb = *(const float4*)&few1[(128 + k) * 128 + eg * 4];
    float a0 = x2s[k], a1 = x2s[128 + k];
    aA[0][0] = fmaf(a0, wa.x, aA[0][0]); aA[0][1] = fmaf(a0, wa.y, aA[0][1]);
    aA[0][2] = fmaf(a0, wa.z, aA[0][2]); aA[0][3] = fmaf(a0, wa.w, aA[0][3]);
    aA[1][0] = fmaf(a1, wa.x, aA[1][0]); aA[1][1] = fmaf(a1, wa.y, aA[1][1]);
    aA[1][2] = fmaf(a1, wa.z, aA[1][2]); aA[1][3] = fmaf(a1, wa.w, aA[1][3]);
    aB[0][0] = fmaf(a0, wb.x, aB[0][0]); aB[0][1] = fmaf(a0, wb.y, aB[0][1]);
    aB[0][2] = fmaf(a0, wb.z, aB[0][2]); aB[0][3] = fmaf(a0, wb.w, aB[0][3]);
    aB[1][0] = fmaf(a1, wb.x, aB[1][0]); aB[1][1] = fmaf(a1, wb.y, aB[1][1]);
    aB[1][2] = fmaf(a1, wb.z, aB[1][2]); aB[1][3] = fmaf(a1, wb.w, aB[1][3]);
  }
  __syncthreads();
#pragma unroll
  for (int r = 0; r < 2; r++)
    *(float4*)&red[ks * 256 + r * 128 + eg * 4] = *(float4*)aA[r];
  __syncthreads();
  {
    float s = 0.0f;
#pragma unroll
    for (int k8 = 0; k8 < 8; k8++) s += red[k8 * 256 + tx];
    int r = tx >> 7, e = tx & 127;
    g_A[(row0 + r) * 128 + e] = s + feb1[e];
  }
  __syncthreads();
#pragma unroll
  for (int r = 0; r < 2; r++)
    *(float4*)&red[ks * 256 + r * 128 + eg * 4] = *(float4*)aB[r];
  __syncthreads();
  {
    float s = 0.0f;
#pragma unroll
    for (int k8 = 0; k8 < 8; k8++) s += red[k8 * 256 + tx];
    int r = tx >> 7, e = tx & 127;
    g_Bm[(row0 + r) * 128 + e] = s;
  }
}

// ---------------- Kernel 5: pairwise edge FFN (A_i + B_j factorized) -------------
__global__ void k_edge(const float* __restrict__ few2, const float* __restrict__ feb2,
                       float* __restrict__ edge) {
  __shared__ float As[4 * 128];
  __shared__ float w2s[128];
  int b = blockIdx.x, tx = threadIdx.x;
  int n = b >> 8, rest = b & 255, ig = rest >> 1, jh = rest & 1;
  int i0 = ig * 4;
  if (tx < 128) w2s[tx] = few2[tx];
  As[tx] = g_A[(n * 512 + i0) * 128 + tx];
  As[tx + 256] = g_A[(n * 512 + i0) * 128 + tx + 256];
  float eb2 = feb2[0];
  __syncthreads();
  int j = jh * 256 + tx;
  const float* B0 = &g_Bm[(n * 512 + j) * 128];
  float acc[4] = {};
#pragma unroll 4
  for (int dc = 0; dc < 32; dc++) {
    float4 bv = *(const float4*)&B0[dc * 4];
    float4 w4 = *(const float4*)&w2s[dc * 4];
#pragma unroll
    for (int i = 0; i < 4; i++) {
      float4 a4 = *(const float4*)&As[i * 128 + dc * 4];
      acc[i] = fmaf(fmaxf(a4.x + bv.x, 0.0f), w4.x, acc[i]);
      acc[i] = fmaf(fmaxf(a4.y + bv.y, 0.0f), w4.y, acc[i]);
      acc[i] = fmaf(fmaxf(a4.z + bv.z, 0.0f), w4.z, acc[i]);
      acc[i] = fmaf(fmaxf(a4.w + bv.w, 0.0f), w4.w, acc[i]);
    }
  }
  const float scale = 1.0f / 512.0f;
#pragma unroll
  for (int i = 0; i < 4; i++)
    edge[(n * 512 + i0 + i) * 512 + j] = (acc[i] + eb2) * scale;
}

extern "C" void kernel_launch(void* const* d_in, const int* in_sizes, int n_in,
                              void* d_out, int out_size, void* d_ws, size_t ws_size,
                              hipStream_t stream) {
  (void)in_sizes; (void)n_in; (void)out_size; (void)d_ws; (void)ws_size;
  const float* x     = (const float*)d_in[0];
  const float* fn_w1 = (const float*)d_in[1];
  const float* fn_b1 = (const float*)d_in[2];
  const float* fn_w2 = (const float*)d_in[3];
  const float* fn_b2 = (const float*)d_in[4];
  const float* wk    = (const float*)d_in[5];
  const float* bk    = (const float*)d_in[6];
  const float* wq    = (const float*)d_in[7];
  const float* bq    = (const float*)d_in[8];
  const float* wv    = (const float*)d_in[9];
  const float* bv    = (const float*)d_in[10];
  const float* fv_w1 = (const float*)d_in[11];
  const float* fv_b1 = (const float*)d_in[12];
  const float* fv_w2 = (const float*)d_in[13];
  const float* fv_b2 = (const float*)d_in[14];
  const float* fe_w1 = (const float*)d_in[15];
  const float* fe_b1 = (const float*)d_in[16];
  const float* fe_w2 = (const float*)d_in[17];
  const float* fe_b2 = (const float*)d_in[18];

  float* x2out = (float*)d_out;      // [0, 131072) floats
  float* edge  = x2out + 131072;     // [131072, 655360) floats

  k_fnode<<<512, 256, 0, stream>>>(x, fn_w1, fn_b1, fn_w2, fn_b2);
  k_kqv<<<768, 256, 0, stream>>>(wk, bk, wq, bq, wv, bv);
  k_attn<<<512, 256, 0, stream>>>();
  k_amerge<<<512, 256, 0, stream>>>();
  k_fv1<<<512, 256, 0, stream>>>(fv_w1);
  k_fv2<<<512, 256, 0, stream>>>(fv_b1, fv_w2, fv_b2, fe_w1, fe_b1, x2out);
  k_edge<<<512, 256, 0, stream>>>(fe_w2, fe_b2, edge);
}

// Round 9
// 148.698 us; speedup vs baseline: 2.7769x; 1.0932x over previous
//
#include <hip/hip_runtime.h>

typedef unsigned short u16;
typedef unsigned int u32;
typedef __attribute__((ext_vector_type(8))) short short8;
typedef __attribute__((ext_vector_type(4))) float f32x4;

__device__ __forceinline__ u16 f2b(float f) {
  union { float f; u32 i; } v; v.f = f;
  u32 i = v.i;
  return (u16)((i + 0x7FFFu + ((i >> 16) & 1u)) >> 16);
}
__device__ __forceinline__ float lo16(u32 x) { union { u32 i; float f; } v; v.i = x << 16; return v.f; }
__device__ __forceinline__ float hi16(u32 x) { union { u32 i; float f; } v; v.i = x & 0xffff0000u; return v.f; }
__device__ __forceinline__ u32 pack2(float a, float b) { return (u32)f2b(a) | ((u32)f2b(b) << 16); }

// Sizes: N=2, M=512, D_IN=64, D=128, H=8. Rows = N*M = 1024. hn = h*2+n in [0,16).
__device__ __align__(16) float g_h[1024 * 128];
__device__ __align__(16) u16   g_hb[1024 * 128];      // h in bf16 for MFMA staging
__device__ __align__(16) u16   g_K[16 * 512 * 128];   // bf16 [hn][m][d]
__device__ __align__(16) u16   g_Q[16 * 512 * 128];
__device__ __align__(16) u16   g_V[16 * 512 * 128];
__device__ __align__(16) float g_Op[512 * 64 * 128];  // flash partials per (hn,it,jc) block
__device__ __align__(16) float g_ml[512 * 64 * 2];
__device__ __align__(16) u16   g_att[1024 * 1024];    // bf16 concat [n*512+m][h*128+e]
__device__ __align__(16) float g_part8[8 * 1024 * 128]; // fv1 K-chunk partials
__device__ __align__(16) float g_A[1024 * 128];
__device__ __align__(16) float g_Bm[1024 * 128];

// ---------------- Kernel 1: f_node, 2 rows/block, float4 weights, K-split --------
__global__ void k_fnode(const float* __restrict__ x, const float* __restrict__ w1,
                        const float* __restrict__ b1, const float* __restrict__ w2,
                        const float* __restrict__ b2) {
  __shared__ float xr[2 * 64];
  __shared__ float hids[2 * 256];
  __shared__ float red[2048];
  int tx = threadIdx.x;
  int row0 = blockIdx.x * 2;
  if (tx < 128) {
    int r = tx >> 6, k = tx & 63;
    xr[tx] = x[(row0 + r) * 64 + k] + sinf((float)k * (5.0f / 63.0f));
  }
  __syncthreads();
  {
    int ks = tx >> 6, cg = tx & 63;
    float acc[2][4] = {};
#pragma unroll 4
    for (int i = 0; i < 16; i++) {
      int k = ks * 16 + i;
      float4 w4 = *(const float4*)&w1[k * 256 + cg * 4];
      float a0 = xr[k], a1 = xr[64 + k];
      acc[0][0] = fmaf(a0, w4.x, acc[0][0]); acc[0][1] = fmaf(a0, w4.y, acc[0][1]);
      acc[0][2] = fmaf(a0, w4.z, acc[0][2]); acc[0][3] = fmaf(a0, w4.w, acc[0][3]);
      acc[1][0] = fmaf(a1, w4.x, acc[1][0]); acc[1][1] = fmaf(a1, w4.y, acc[1][1]);
      acc[1][2] = fmaf(a1, w4.z, acc[1][2]); acc[1][3] = fmaf(a1, w4.w, acc[1][3]);
    }
#pragma unroll
    for (int r = 0; r < 2; r++)
      *(float4*)&red[ks * 512 + r * 256 + cg * 4] = *(float4*)acc[r];
  }
  __syncthreads();
#pragma unroll
  for (int jo = 0; jo < 2; jo++) {
    int o = jo * 256 + tx;
    float s = red[o] + red[512 + o] + red[1024 + o] + red[1536 + o];
    hids[o] = fmaxf(s + b1[o & 255], 0.0f);
  }
  __syncthreads();
  {
    int ks = tx >> 5, eg = tx & 31;
    float acc[2][4] = {};
#pragma unroll 4
    for (int i = 0; i < 32; i++) {
      int k = ks * 32 + i;
      float4 w4 = *(const float4*)&w2[k * 128 + eg * 4];
      float a0 = hids[k], a1 = hids[256 + k];
      acc[0][0] = fmaf(a0, w4.x, acc[0][0]); acc[0][1] = fmaf(a0, w4.y, acc[0][1]);
      acc[0][2] = fmaf(a0, w4.z, acc[0][2]); acc[0][3] = fmaf(a0, w4.w, acc[0][3]);
      acc[1][0] = fmaf(a1, w4.x, acc[1][0]); acc[1][1] = fmaf(a1, w4.y, acc[1][1]);
      acc[1][2] = fmaf(a1, w4.z, acc[1][2]); acc[1][3] = fmaf(a1, w4.w, acc[1][3]);
    }
    __syncthreads();
#pragma unroll
    for (int r = 0; r < 2; r++)
      *(float4*)&red[ks * 256 + r * 128 + eg * 4] = *(float4*)acc[r];
  }
  __syncthreads();
  {
    float s = 0.0f;
#pragma unroll
    for (int ks = 0; ks < 8; ks++) s += red[ks * 256 + tx];
    int r = tx >> 7, e = tx & 127;
    float v = s + b2[e];
    g_h[(row0 + r) * 128 + e] = v;
    g_hb[(row0 + r) * 128 + e] = f2b(v);
  }
}

// ---------------- Kernel 2: K/Q/V projections via MFMA ---------------------------
// b = ph*16 + rt: ph = proj*8+head (24), rt = row-tile (16 x 64 rows).
// A = W^T (m=e), B = h rows (n=row); D[e=quad*4+reg][row=cl].
__global__ __launch_bounds__(256) void k_kqv(
    const float* __restrict__ wk, const float* __restrict__ bk,
    const float* __restrict__ wq, const float* __restrict__ bq,
    const float* __restrict__ wv, const float* __restrict__ bv) {
  __shared__ u16 hs[64 * 136];
  __shared__ u16 Wt[128 * 136];   // W^T[e][d] bf16
  int b = blockIdx.x, tx = threadIdx.x;
  int rt = b & 15, ph = b >> 4;
  int proj = ph >> 3, head = ph & 7;
  const float* W  = (proj == 0) ? wk : (proj == 1) ? wq : wv;
  const float* Bb = (proj == 0) ? bk : (proj == 1) ? bq : bv;
  u16* O = (proj == 0) ? g_K : (proj == 1) ? g_Q : g_V;
  int r0 = rt * 64;
#pragma unroll
  for (int t = 0; t < 4; t++) {
    int idx = t * 256 + tx, row = idx >> 4, oct = idx & 15;
    *(uint4*)&hs[row * 136 + oct * 8] = *(const uint4*)&g_hb[(r0 + row) * 128 + oct * 8];
  }
  const float* Wh = W + head * 16384;
  {
    int dg = (tx & 31) * 4;
#pragma unroll
    for (int half = 0; half < 2; half++) {
      int e8 = ((tx >> 5) + half * 8) * 8;
      float rr[4][8];
#pragma unroll
      for (int r = 0; r < 4; r++) {
        float4 a = *(const float4*)&Wh[(dg + r) * 128 + e8];
        float4 c = *(const float4*)&Wh[(dg + r) * 128 + e8 + 4];
        rr[r][0] = a.x; rr[r][1] = a.y; rr[r][2] = a.z; rr[r][3] = a.w;
        rr[r][4] = c.x; rr[r][5] = c.y; rr[r][6] = c.z; rr[r][7] = c.w;
      }
#pragma unroll
      for (int c = 0; c < 8; c++)
        *(uint2*)&Wt[(e8 + c) * 136 + dg] =
            make_uint2(pack2(rr[0][c], rr[1][c]), pack2(rr[2][c], rr[3][c]));
    }
  }
  __syncthreads();
  int lane = tx & 63, wv_ = tx >> 6, cl = lane & 15, quad = lane >> 4;
  short8 bH[4];
#pragma unroll
  for (int kk = 0; kk < 4; kk++)
    bH[kk] = *(const short8*)&hs[(wv_ * 16 + cl) * 136 + kk * 32 + quad * 8];
  f32x4 zero = {0.0f, 0.0f, 0.0f, 0.0f};
  f32x4 acc[8];
#pragma unroll
  for (int em = 0; em < 8; em++) acc[em] = zero;
#pragma unroll
  for (int em = 0; em < 8; em++)
#pragma unroll
    for (int kk = 0; kk < 4; kk++) {
      short8 aW = *(const short8*)&Wt[(em * 16 + cl) * 136 + kk * 32 + quad * 8];
      acc[em] = __builtin_amdgcn_mfma_f32_16x16x32_bf16(aW, bH[kk], acc[em], 0, 0, 0);
    }
#pragma unroll
  for (int em = 0; em < 8; em++) {
    float4 b4 = *(const float4*)&Bb[head * 128 + em * 16 + quad * 4];
    uint2 st = make_uint2(pack2(acc[em][0] + b4.x, acc[em][1] + b4.y),
                          pack2(acc[em][2] + b4.z, acc[em][3] + b4.w));
    *(uint2*)&O[(head * 1024 + r0 + wv_ * 16 + cl) * 128 + em * 16 + quad * 4] = st;
  }
}

// ---------------- Kernel 3: attention via MFMA 16x16x32 bf16 ---------------------
__global__ __launch_bounds__(256) void k_attn() {
  __shared__ u16 Ks[64 * 136];
  __shared__ u16 Qs[64 * 136];
  __shared__ u16 Vt[128 * 72];
  __shared__ u16 Pw[4 * 16 * 72];
  __shared__ float alphas[4 * 16];
  int b = blockIdx.x, tx = threadIdx.x;
  int jc = b & 3, it = (b >> 2) & 7, hn = b >> 5;
  int i0 = it * 64;
  const u16* Kp = g_K + hn * 65536;
  const u16* Qp = g_Q + hn * 65536;
  const u16* Vp = g_V + hn * 65536;
#pragma unroll
  for (int t = 0; t < 4; t++) {
    int idx = t * 256 + tx, row = idx >> 4, oct = idx & 15;
    *(uint4*)&Ks[row * 136 + oct * 8] = *(const uint4*)&Kp[(i0 + row) * 128 + oct * 8];
  }
  int lane = tx & 63, wv = tx >> 6;
  int cl = lane & 15, quad = lane >> 4;
  f32x4 zero = {0.0f, 0.0f, 0.0f, 0.0f};
  f32x4 o[8];
#pragma unroll
  for (int es = 0; es < 8; es++) o[es] = zero;
  float m_ = -1e30f, l_ = 0.0f;

  for (int jt = 0; jt < 2; jt++) {
    int j0 = jc * 128 + jt * 64;
    __syncthreads();
#pragma unroll
    for (int t = 0; t < 4; t++) {
      int idx = t * 256 + tx, row = idx >> 4, oct = idx & 15;
      *(uint4*)&Qs[row * 136 + oct * 8] = *(const uint4*)&Qp[(j0 + row) * 128 + oct * 8];
    }
    {
      int jg = (tx & 15) * 4, e8 = (tx >> 4) * 8;
      uint4 r0 = *(const uint4*)&Vp[(j0 + jg + 0) * 128 + e8];
      uint4 r1 = *(const uint4*)&Vp[(j0 + jg + 1) * 128 + e8];
      uint4 r2 = *(const uint4*)&Vp[(j0 + jg + 2) * 128 + e8];
      uint4 r3 = *(const uint4*)&Vp[(j0 + jg + 3) * 128 + e8];
      const u32* p0 = (const u32*)&r0; const u32* p1 = (const u32*)&r1;
      const u32* p2 = (const u32*)&r2; const u32* p3 = (const u32*)&r3;
#pragma unroll
      for (int c = 0; c < 8; c++) {
        int w = c >> 1, sh = (c & 1) * 16;
        u32 lo = ((p0[w] >> sh) & 0xffffu) | (((p1[w] >> sh) & 0xffffu) << 16);
        u32 hi = ((p2[w] >> sh) & 0xffffu) | (((p3[w] >> sh) & 0xffffu) << 16);
        *(uint2*)&Vt[(e8 + c) * 72 + jg] = make_uint2(lo, hi);
      }
    }
    __syncthreads();
    short8 bK[4];
#pragma unroll
    for (int kk = 0; kk < 4; kk++)
      bK[kk] = *(const short8*)&Ks[(wv * 16 + cl) * 136 + kk * 32 + quad * 8];
    f32x4 st[4];
#pragma unroll
    for (int s = 0; s < 4; s++) {
      f32x4 acc = zero;
#pragma unroll
      for (int kk = 0; kk < 4; kk++) {
        short8 aQ = *(const short8*)&Qs[(s * 16 + cl) * 136 + kk * 32 + quad * 8];
        acc = __builtin_amdgcn_mfma_f32_16x16x32_bf16(aQ, bK[kk], acc, 0, 0, 0);
      }
      st[s] = acc;
    }
    float p[4][4];
    float tm = -1e30f;
#pragma unroll
    for (int s = 0; s < 4; s++)
#pragma unroll
      for (int r = 0; r < 4; r++) {
        float v = st[s][r];
        v = fmaxf(v, 0.2f * v);
        p[s][r] = v;
        tm = fmaxf(tm, v);
      }
    tm = fmaxf(tm, __shfl_xor(tm, 16));
    tm = fmaxf(tm, __shfl_xor(tm, 32));
    float mn = fmaxf(m_, tm);
    float alpha = __expf(m_ - mn);
    m_ = mn;
    float ps = 0.0f;
#pragma unroll
    for (int s = 0; s < 4; s++)
#pragma unroll
      for (int r = 0; r < 4; r++) {
        float e = __expf(p[s][r] - mn);
        p[s][r] = e;
        ps += e;
      }
    ps += __shfl_xor(ps, 16);
    ps += __shfl_xor(ps, 32);
    l_ = l_ * alpha + ps;
#pragma unroll
    for (int s = 0; s < 4; s++) {
      uint2 w2v = make_uint2(pack2(p[s][0], p[s][1]), pack2(p[s][2], p[s][3]));
      *(uint2*)&Pw[(wv * 16 + cl) * 72 + s * 16 + quad * 4] = w2v;
    }
    if (quad == 0) alphas[wv * 16 + cl] = alpha;
    __syncthreads();
    f32x4 av = *(const f32x4*)&alphas[wv * 16 + quad * 4];
#pragma unroll
    for (int es = 0; es < 8; es++) o[es] *= av;
    short8 aP[2];
#pragma unroll
    for (int k2 = 0; k2 < 2; k2++)
      aP[k2] = *(const short8*)&Pw[(wv * 16 + cl) * 72 + k2 * 32 + quad * 8];
#pragma unroll
    for (int es = 0; es < 8; es++) {
#pragma unroll
      for (int k2 = 0; k2 < 2; k2++) {
        short8 bV = *(const short8*)&Vt[(es * 16 + cl) * 72 + k2 * 32 + quad * 8];
        o[es] = __builtin_amdgcn_mfma_f32_16x16x32_bf16(aP[k2], bV, o[es], 0, 0, 0);
      }
    }
  }
#pragma unroll
  for (int es = 0; es < 8; es++)
#pragma unroll
    for (int r = 0; r < 4; r++)
      g_Op[(b * 64 + wv * 16 + quad * 4 + r) * 128 + es * 16 + cl] = o[es][r];
  if (quad == 0) {
    g_ml[(b * 64 + wv * 16 + cl) * 2 + 0] = m_;
    g_ml[(b * 64 + wv * 16 + cl) * 2 + 1] = l_;
  }
}

// ---------------- Kernel 3b: merge 4 j-chunk partials -> g_att (bf16) ------------
__global__ void k_amerge() {
  int b = blockIdx.x, tx = threadIdx.x;
  int hn = b >> 5, ig = b & 31;
  int row = ig * 16 + (tx >> 4);
  int c8 = (tx & 15) * 8;
  int it = row >> 6, lr = row & 63;
  float mc[4], lc[4];
  float4 oa[4], ob[4];
#pragma unroll
  for (int c = 0; c < 4; c++) {
    int bp = hn * 32 + it * 4 + c;
    float2 ml = *(const float2*)&g_ml[(bp * 64 + lr) * 2];
    mc[c] = ml.x; lc[c] = ml.y;
    oa[c] = *(const float4*)&g_Op[(bp * 64 + lr) * 128 + c8];
    ob[c] = *(const float4*)&g_Op[(bp * 64 + lr) * 128 + c8 + 4];
  }
  float ms = fmaxf(fmaxf(mc[0], mc[1]), fmaxf(mc[2], mc[3]));
  float lsum = 0.0f;
  float ra[8] = {};
#pragma unroll
  for (int c = 0; c < 4; c++) {
    float w = __expf(mc[c] - ms);
    lsum += w * lc[c];
    ra[0] = fmaf(w, oa[c].x, ra[0]); ra[1] = fmaf(w, oa[c].y, ra[1]);
    ra[2] = fmaf(w, oa[c].z, ra[2]); ra[3] = fmaf(w, oa[c].w, ra[3]);
    ra[4] = fmaf(w, ob[c].x, ra[4]); ra[5] = fmaf(w, ob[c].y, ra[5]);
    ra[6] = fmaf(w, ob[c].z, ra[6]); ra[7] = fmaf(w, ob[c].w, ra[7]);
  }
  float inv = 1.0f / lsum;
  u16 pk[8];
#pragma unroll
  for (int e = 0; e < 8; e++) {
    float v = ra[e] * inv;
    v = fmaxf(v, 0.2f * v);
    pk[e] = f2b(v);
  }
  int h = hn >> 1, n = hn & 1;
  uint4 st;
  st.x = (u32)pk[0] | ((u32)pk[1] << 16);
  st.y = (u32)pk[2] | ((u32)pk[3] << 16);
  st.z = (u32)pk[4] | ((u32)pk[5] << 16);
  st.w = (u32)pk[6] | ((u32)pk[7] << 16);
  *(uint4*)&g_att[(n * 512 + row) * 1024 + h * 128 + c8] = st;
}

// ---------------- Kernel 4a: att@fv_w1 via MFMA, 8-way K-chunk partials ----------
// b = rt*8 + kc: rt row-tile (16 x 64 rows), kc K-chunk (8 x 128).
__global__ __launch_bounds__(256) void k_fv1(const float* __restrict__ w1) {
  __shared__ u16 atts[64 * 136];
  __shared__ u16 w1t[128 * 136];   // w1_chunk^T[e][k] bf16
  int b = blockIdx.x, tx = threadIdx.x;
  int kc = b & 7, rt = b >> 3;
  int r0 = rt * 64, k0 = kc * 128;
#pragma unroll
  for (int t = 0; t < 4; t++) {
    int idx = t * 256 + tx, row = idx >> 4, oct = idx & 15;
    *(uint4*)&atts[row * 136 + oct * 8] =
        *(const uint4*)&g_att[(r0 + row) * 1024 + k0 + oct * 8];
  }
  {
    int dg = (tx & 31) * 4;
#pragma unroll
    for (int half = 0; half < 2; half++) {
      int e8 = ((tx >> 5) + half * 8) * 8;
      float rr[4][8];
#pragma unroll
      for (int r = 0; r < 4; r++) {
        float4 a = *(const float4*)&w1[(k0 + dg + r) * 128 + e8];
        float4 c = *(const float4*)&w1[(k0 + dg + r) * 128 + e8 + 4];
        rr[r][0] = a.x; rr[r][1] = a.y; rr[r][2] = a.z; rr[r][3] = a.w;
        rr[r][4] = c.x; rr[r][5] = c.y; rr[r][6] = c.z; rr[r][7] = c.w;
      }
#pragma unroll
      for (int c = 0; c < 8; c++)
        *(uint2*)&w1t[(e8 + c) * 136 + dg] =
            make_uint2(pack2(rr[0][c], rr[1][c]), pack2(rr[2][c], rr[3][c]));
    }
  }
  __syncthreads();
  int lane = tx & 63, wv_ = tx >> 6, cl = lane & 15, quad = lane >> 4;
  short8 bA[4];
#pragma unroll
  for (int kk = 0; kk < 4; kk++)
    bA[kk] = *(const short8*)&atts[(wv_ * 16 + cl) * 136 + kk * 32 + quad * 8];
  f32x4 zero = {0.0f, 0.0f, 0.0f, 0.0f};
  f32x4 acc[8];
#pragma unroll
  for (int em = 0; em < 8; em++) acc[em] = zero;
#pragma unroll
  for (int em = 0; em < 8; em++)
#pragma unroll
    for (int kk = 0; kk < 4; kk++) {
      short8 aW = *(const short8*)&w1t[(em * 16 + cl) * 136 + kk * 32 + quad * 8];
      acc[em] = __builtin_amdgcn_mfma_f32_16x16x32_bf16(aW, bA[kk], acc[em], 0, 0, 0);
    }
#pragma unroll
  for (int em = 0; em < 8; em++)
    *(f32x4*)&g_part8[kc * 131072 + (r0 + wv_ * 16 + cl) * 128 + em * 16 + quad * 4] =
        acc[em];
}

// ---------------- Kernel 4b: bias+relu, @fv_w2, residual, A/B projections --------
__global__ void k_fv2(const float* __restrict__ b1, const float* __restrict__ w2,
                      const float* __restrict__ b2, const float* __restrict__ few1,
                      const float* __restrict__ feb1, float* __restrict__ x2out) {
  __shared__ float hids[2 * 128];
  __shared__ float x2s[2 * 128];
  __shared__ float red[8 * 256];
  int b = blockIdx.x, tx = threadIdx.x;
  int row0 = b * 2;
  {
    int r = tx >> 7, e = tx & 127;
    int gi = (row0 + r) * 128 + e;
    float s = b1[e];
#pragma unroll
    for (int kc = 0; kc < 8; kc++) s += g_part8[kc * 131072 + gi];
    hids[tx] = fmaxf(s, 0.0f);
  }
  __syncthreads();
  int ks = tx >> 5, eg = tx & 31;
  {
    float acc[2][4] = {};
#pragma unroll 4
    for (int i = 0; i < 16; i++) {
      int k = ks * 16 + i;
      float4 w4 = *(const float4*)&w2[k * 128 + eg * 4];
      float a0 = hids[k], a1 = hids[128 + k];
      acc[0][0] = fmaf(a0, w4.x, acc[0][0]); acc[0][1] = fmaf(a0, w4.y, acc[0][1]);
      acc[0][2] = fmaf(a0, w4.z, acc[0][2]); acc[0][3] = fmaf(a0, w4.w, acc[0][3]);
      acc[1][0] = fmaf(a1, w4.x, acc[1][0]); acc[1][1] = fmaf(a1, w4.y, acc[1][1]);
      acc[1][2] = fmaf(a1, w4.z, acc[1][2]); acc[1][3] = fmaf(a1, w4.w, acc[1][3]);
    }
#pragma unroll
    for (int r = 0; r < 2; r++)
      *(float4*)&red[ks * 256 + r * 128 + eg * 4] = *(float4*)acc[r];
  }
  __syncthreads();
  {
    float s = 0.0f;
#pragma unroll
    for (int k8 = 0; k8 < 8; k8++) s += red[k8 * 256 + tx];
    int r = tx >> 7, e = tx & 127;
    int gi = (row0 + r) * 128 + e;
    float c = s + b2[e] + g_h[gi];
    x2s[tx] = c;
    x2out[gi] = c;
  }
  __syncthreads();
  float aA[2][4] = {}, aB[2][4] = {};
#pragma unroll 4
  for (int i = 0; i < 16; i++) {
    int k = ks * 16 + i;
    float4 wa = *(const float4*)&few1[k * 128 + eg * 4];
    float4 wb = *(const float4*)&few1[(128 + k) * 128 + eg * 4];
    float a0 = x2s[k], a1 = x2s[128 + k];
    aA[0][0] = fmaf(a0, wa.x, aA[0][0]); aA[0][1] = fmaf(a0, wa.y, aA[0][1]);
    aA[0][2] = fmaf(a0, wa.z, aA[0][2]); aA[0][3] = fmaf(a0, wa.w, aA[0][3]);
    aA[1][0] = fmaf(a1, wa.x, aA[1][0]); aA[1][1] = fmaf(a1, wa.y, aA[1][1]);
    aA[1][2] = fmaf(a1, wa.z, aA[1][2]); aA[1][3] = fmaf(a1, wa.w, aA[1][3]);
    aB[0][0] = fmaf(a0, wb.x, aB[0][0]); aB[0][1] = fmaf(a0, wb.y, aB[0][1]);
    aB[0][2] = fmaf(a0, wb.z, aB[0][2]); aB[0][3] = fmaf(a0, wb.w, aB[0][3]);
    aB[1][0] = fmaf(a1, wb.x, aB[1][0]); aB[1][1] = fmaf(a1, wb.y, aB[1][1]);
    aB[1][2] = fmaf(a1, wb.z, aB[1][2]); aB[1][3] = fmaf(a1, wb.w, aB[1][3]);
  }
  __syncthreads();
#pragma unroll
  for (int r = 0; r < 2; r++)
    *(float4*)&red[ks * 256 + r * 128 + eg * 4] = *(float4*)aA[r];
  __syncthreads();
  {
    float s = 0.0f;
#pragma unroll
    for (int k8 = 0; k8 < 8; k8++) s += red[k8 * 256 + tx];
    int r = tx >> 7, e = tx & 127;
    g_A[(row0 + r) * 128 + e] = s + feb1[e];
  }
  __syncthreads();
#pragma unroll
  for (int r = 0; r < 2; r++)
    *(float4*)&red[ks * 256 + r * 128 + eg * 4] = *(float4*)aB[r];
  __syncthreads();
  {
    float s = 0.0f;
#pragma unroll
    for (int k8 = 0; k8 < 8; k8++) s += red[k8 * 256 + tx];
    int r = tx >> 7, e = tx & 127;
    g_Bm[(row0 + r) * 128 + e] = s;
  }
}

// ---------------- Kernel 5: pairwise edge FFN (A_i + B_j factorized) -------------
__global__ void k_edge(const float* __restrict__ few2, const float* __restrict__ feb2,
                       float* __restrict__ edge) {
  __shared__ float As[4 * 128];
  __shared__ float w2s[128];
  int b = blockIdx.x, tx = threadIdx.x;
  int n = b >> 8, rest = b & 255, ig = rest >> 1, jh = rest & 1;
  int i0 = ig * 4;
  if (tx < 128) w2s[tx] = few2[tx];
  As[tx] = g_A[(n * 512 + i0) * 128 + tx];
  As[tx + 256] = g_A[(n * 512 + i0) * 128 + tx + 256];
  float eb2 = feb2[0];
  __syncthreads();
  int j = jh * 256 + tx;
  const float* B0 = &g_Bm[(n * 512 + j) * 128];
  float acc[4] = {};
#pragma unroll 4
  for (int dc = 0; dc < 32; dc++) {
    float4 bv = *(const float4*)&B0[dc * 4];
    float4 w4 = *(const float4*)&w2s[dc * 4];
#pragma unroll
    for (int i = 0; i < 4; i++) {
      float4 a4 = *(const float4*)&As[i * 128 + dc * 4];
      acc[i] = fmaf(fmaxf(a4.x + bv.x, 0.0f), w4.x, acc[i]);
      acc[i] = fmaf(fmaxf(a4.y + bv.y, 0.0f), w4.y, acc[i]);
      acc[i] = fmaf(fmaxf(a4.z + bv.z, 0.0f), w4.z, acc[i]);
      acc[i] = fmaf(fmaxf(a4.w + bv.w, 0.0f), w4.w, acc[i]);
    }
  }
  const float scale = 1.0f / 512.0f;
#pragma unroll
  for (int i = 0; i < 4; i++)
    edge[(n * 512 + i0 + i) * 512 + j] = (acc[i] + eb2) * scale;
}

extern "C" void kernel_launch(void* const* d_in, const int* in_sizes, int n_in,
                              void* d_out, int out_size, void* d_ws, size_t ws_size,
                              hipStream_t stream) {
  (void)in_sizes; (void)n_in; (void)out_size; (void)d_ws; (void)ws_size;
  const float* x     = (const float*)d_in[0];
  const float* fn_w1 = (const float*)d_in[1];
  const float* fn_b1 = (const float*)d_in[2];
  const float* fn_w2 = (const float*)d_in[3];
  const float* fn_b2 = (const float*)d_in[4];
  const float* wk    = (const float*)d_in[5];
  const float* bk    = (const float*)d_in[6];
  const float* wq    = (const float*)d_in[7];
  const float* bq    = (const float*)d_in[8];
  const float* wv    = (const float*)d_in[9];
  const float* bv    = (const float*)d_in[10];
  const float* fv_w1 = (const float*)d_in[11];
  const float* fv_b1 = (const float*)d_in[12];
  const float* fv_w2 = (const float*)d_in[13];
  const float* fv_b2 = (const float*)d_in[14];
  const float* fe_w1 = (const float*)d_in[15];
  const float* fe_b1 = (const float*)d_in[16];
  const float* fe_w2 = (const float*)d_in[17];
  const float* fe_b2 = (const float*)d_in[18];

  float* x2out = (float*)d_out;      // [0, 131072) floats
  float* edge  = x2out + 131072;     // [131072, 655360) floats

  k_fnode<<<512, 256, 0, stream>>>(x, fn_w1, fn_b1, fn_w2, fn_b2);
  k_kqv<<<384, 256, 0, stream>>>(wk, bk, wq, bq, wv, bv);
  k_attn<<<512, 256, 0, stream>>>();
  k_amerge<<<512, 256, 0, stream>>>();
  k_fv1<<<128, 256, 0, stream>>>(fv_w1);
  k_fv2<<<512, 256, 0, stream>>>(fv_b1, fv_w2, fv_b2, fe_w1, fe_b1, x2out);
  k_edge<<<512, 256, 0, stream>>>(fe_w2, fe_b2, edge);
}

// Round 10
// 143.556 us; speedup vs baseline: 2.8763x; 1.0358x over previous
//
#include <hip/hip_runtime.h>

typedef unsigned short u16;
typedef unsigned int u32;
typedef __attribute__((ext_vector_type(8))) short short8;
typedef __attribute__((ext_vector_type(4))) float f32x4;

__device__ __forceinline__ u16 f2b(float f) {
  union { float f; u32 i; } v; v.f = f;
  u32 i = v.i;
  return (u16)((i + 0x7FFFu + ((i >> 16) & 1u)) >> 16);
}
__device__ __forceinline__ float lo16(u32 x) { union { u32 i; float f; } v; v.i = x << 16; return v.f; }
__device__ __forceinline__ float hi16(u32 x) { union { u32 i; float f; } v; v.i = x & 0xffff0000u; return v.f; }
__device__ __forceinline__ u32 pack2(float a, float b) { return (u32)f2b(a) | ((u32)f2b(b) << 16); }

// Sizes: N=2, M=512, D_IN=64, D=128, H=8. Rows = N*M = 1024. hn = h*2+n in [0,16).
__device__ __align__(16) float g_h[1024 * 128];
__device__ __align__(16) u16   g_hb[1024 * 128];
__device__ __align__(16) u16   g_Wt[24 * 128 * 128];   // W^T per (proj,head): [ph][e][d] bf16
__device__ __align__(16) u16   g_w1t[128 * 1024];      // fv_w1^T: [e][k] bf16
__device__ __align__(16) u16   g_K[16 * 512 * 128];
__device__ __align__(16) u16   g_Q[16 * 512 * 128];
__device__ __align__(16) u16   g_V[16 * 512 * 128];
__device__ __align__(16) u16   g_Opb[512 * 64 * 128];  // bf16 flash partials
__device__ __align__(16) float g_ml[512 * 64 * 2];
__device__ __align__(16) float g_part8[8 * 1024 * 128];
__device__ __align__(16) float g_A[1024 * 128];
__device__ __align__(16) float g_Bm[1024 * 128];

// ---------------- Kernel 1: f_node (+ weight pre-transpose piggyback) ------------
__global__ void k_fnode(const float* __restrict__ x, const float* __restrict__ w1,
                        const float* __restrict__ b1, const float* __restrict__ w2,
                        const float* __restrict__ b2, const float* __restrict__ wk,
                        const float* __restrict__ wq, const float* __restrict__ wv,
                        const float* __restrict__ fvw1) {
  __shared__ float xr[2 * 64];
  __shared__ float hids[2 * 256];
  __shared__ float red[2048];
  int tx = threadIdx.x;
  int row0 = blockIdx.x * 2;
  if (tx < 128) {
    int r = tx >> 6, k = tx & 63;
    xr[tx] = x[(row0 + r) * 64 + k] + sinf((float)k * (5.0f / 63.0f));
  }
  // piggyback: transpose weights to bf16 (independent of the MLP below)
  {
    int base = blockIdx.x * 1024 + tx;
#pragma unroll
    for (int t = 0; t < 4; t++) {
      int idx = base + t * 256;
      if (idx < 393216) {
        int ph = idx >> 14, rem = idx & 16383, e = rem >> 7, d = rem & 127;
        int proj = ph >> 3, head = ph & 7;
        const float* W = (proj == 0) ? wk : (proj == 1) ? wq : wv;
        g_Wt[idx] = f2b(W[head * 16384 + d * 128 + e]);
      } else {
        int idx2 = idx - 393216;          // [0, 131072)
        int e = idx2 >> 10, k = idx2 & 1023;
        g_w1t[idx2] = f2b(fvw1[k * 128 + e]);
      }
    }
  }
  __syncthreads();
  {
    int ks = tx >> 6, cg = tx & 63;
    float acc[2][4] = {};
#pragma unroll 4
    for (int i = 0; i < 16; i++) {
      int k = ks * 16 + i;
      float4 w4 = *(const float4*)&w1[k * 256 + cg * 4];
      float a0 = xr[k], a1 = xr[64 + k];
      acc[0][0] = fmaf(a0, w4.x, acc[0][0]); acc[0][1] = fmaf(a0, w4.y, acc[0][1]);
      acc[0][2] = fmaf(a0, w4.z, acc[0][2]); acc[0][3] = fmaf(a0, w4.w, acc[0][3]);
      acc[1][0] = fmaf(a1, w4.x, acc[1][0]); acc[1][1] = fmaf(a1, w4.y, acc[1][1]);
      acc[1][2] = fmaf(a1, w4.z, acc[1][2]); acc[1][3] = fmaf(a1, w4.w, acc[1][3]);
    }
#pragma unroll
    for (int r = 0; r < 2; r++)
      *(float4*)&red[ks * 512 + r * 256 + cg * 4] = *(float4*)acc[r];
  }
  __syncthreads();
#pragma unroll
  for (int jo = 0; jo < 2; jo++) {
    int o = jo * 256 + tx;
    float s = red[o] + red[512 + o] + red[1024 + o] + red[1536 + o];
    hids[o] = fmaxf(s + b1[o & 255], 0.0f);
  }
  __syncthreads();
  {
    int ks = tx >> 5, eg = tx & 31;
    float acc[2][4] = {};
#pragma unroll 4
    for (int i = 0; i < 32; i++) {
      int k = ks * 32 + i;
      float4 w4 = *(const float4*)&w2[k * 128 + eg * 4];
      float a0 = hids[k], a1 = hids[256 + k];
      acc[0][0] = fmaf(a0, w4.x, acc[0][0]); acc[0][1] = fmaf(a0, w4.y, acc[0][1]);
      acc[0][2] = fmaf(a0, w4.z, acc[0][2]); acc[0][3] = fmaf(a0, w4.w, acc[0][3]);
      acc[1][0] = fmaf(a1, w4.x, acc[1][0]); acc[1][1] = fmaf(a1, w4.y, acc[1][1]);
      acc[1][2] = fmaf(a1, w4.z, acc[1][2]); acc[1][3] = fmaf(a1, w4.w, acc[1][3]);
    }
    __syncthreads();
#pragma unroll
    for (int r = 0; r < 2; r++)
      *(float4*)&red[ks * 256 + r * 128 + eg * 4] = *(float4*)acc[r];
  }
  __syncthreads();
  {
    float s = 0.0f;
#pragma unroll
    for (int ks = 0; ks < 8; ks++) s += red[ks * 256 + tx];
    int r = tx >> 7, e = tx & 127;
    float v = s + b2[e];
    g_h[(row0 + r) * 128 + e] = v;
    g_hb[(row0 + r) * 128 + e] = f2b(v);
  }
}

// ---------------- Kernel 2: K/Q/V projections via MFMA (pre-transposed W) --------
__global__ __launch_bounds__(256) void k_kqv(
    const float* __restrict__ bk, const float* __restrict__ bq,
    const float* __restrict__ bv) {
  __shared__ u16 hs[64 * 136];
  __shared__ u16 Wt[128 * 136];
  int b = blockIdx.x, tx = threadIdx.x;
  int rt = b & 15, ph = b >> 4;
  int proj = ph >> 3, head = ph & 7;
  const float* Bb = (proj == 0) ? bk : (proj == 1) ? bq : bv;
  u16* O = (proj == 0) ? g_K : (proj == 1) ? g_Q : g_V;
  int r0 = rt * 64;
#pragma unroll
  for (int t = 0; t < 4; t++) {
    int idx = t * 256 + tx, row = idx >> 4, oct = idx & 15;
    *(uint4*)&hs[row * 136 + oct * 8] = *(const uint4*)&g_hb[(r0 + row) * 128 + oct * 8];
  }
  const u16* Wtg = g_Wt + ph * 16384;
#pragma unroll
  for (int t = 0; t < 8; t++) {
    int idx = t * 256 + tx, row = idx >> 4, oct = idx & 15;
    *(uint4*)&Wt[row * 136 + oct * 8] = *(const uint4*)&Wtg[row * 128 + oct * 8];
  }
  __syncthreads();
  int lane = tx & 63, wv_ = tx >> 6, cl = lane & 15, quad = lane >> 4;
  short8 bH[4];
#pragma unroll
  for (int kk = 0; kk < 4; kk++)
    bH[kk] = *(const short8*)&hs[(wv_ * 16 + cl) * 136 + kk * 32 + quad * 8];
  f32x4 zero = {0.0f, 0.0f, 0.0f, 0.0f};
  f32x4 acc[8];
#pragma unroll
  for (int em = 0; em < 8; em++) acc[em] = zero;
#pragma unroll
  for (int em = 0; em < 8; em++)
#pragma unroll
    for (int kk = 0; kk < 4; kk++) {
      short8 aW = *(const short8*)&Wt[(em * 16 + cl) * 136 + kk * 32 + quad * 8];
      acc[em] = __builtin_amdgcn_mfma_f32_16x16x32_bf16(aW, bH[kk], acc[em], 0, 0, 0);
    }
#pragma unroll
  for (int em = 0; em < 8; em++) {
    float4 b4 = *(const float4*)&Bb[head * 128 + em * 16 + quad * 4];
    uint2 st = make_uint2(pack2(acc[em][0] + b4.x, acc[em][1] + b4.y),
                          pack2(acc[em][2] + b4.z, acc[em][3] + b4.w));
    *(uint2*)&O[(head * 1024 + r0 + wv_ * 16 + cl) * 128 + em * 16 + quad * 4] = st;
  }
}

// ---------------- Kernel 3: attention via MFMA, bf16 partials out ----------------
__global__ __launch_bounds__(256) void k_attn() {
  __shared__ u16 Ks[64 * 136];
  __shared__ u16 Qs[64 * 136];
  __shared__ u16 Vt[128 * 72];
  __shared__ u16 Pw[4 * 16 * 72];
  __shared__ float alphas[4 * 16];
  int b = blockIdx.x, tx = threadIdx.x;
  int jc = b & 3, it = (b >> 2) & 7, hn = b >> 5;
  int i0 = it * 64;
  const u16* Kp = g_K + hn * 65536;
  const u16* Qp = g_Q + hn * 65536;
  const u16* Vp = g_V + hn * 65536;
#pragma unroll
  for (int t = 0; t < 4; t++) {
    int idx = t * 256 + tx, row = idx >> 4, oct = idx & 15;
    *(uint4*)&Ks[row * 136 + oct * 8] = *(const uint4*)&Kp[(i0 + row) * 128 + oct * 8];
  }
  int lane = tx & 63, wv = tx >> 6;
  int cl = lane & 15, quad = lane >> 4;
  f32x4 zero = {0.0f, 0.0f, 0.0f, 0.0f};
  f32x4 o[8];
#pragma unroll
  for (int es = 0; es < 8; es++) o[es] = zero;
  float m_ = -1e30f, l_ = 0.0f;

  for (int jt = 0; jt < 2; jt++) {
    int j0 = jc * 128 + jt * 64;
    __syncthreads();
#pragma unroll
    for (int t = 0; t < 4; t++) {
      int idx = t * 256 + tx, row = idx >> 4, oct = idx & 15;
      *(uint4*)&Qs[row * 136 + oct * 8] = *(const uint4*)&Qp[(j0 + row) * 128 + oct * 8];
    }
    {
      int jg = (tx & 15) * 4, e8 = (tx >> 4) * 8;
      uint4 r0 = *(const uint4*)&Vp[(j0 + jg + 0) * 128 + e8];
      uint4 r1 = *(const uint4*)&Vp[(j0 + jg + 1) * 128 + e8];
      uint4 r2 = *(const uint4*)&Vp[(j0 + jg + 2) * 128 + e8];
      uint4 r3 = *(const uint4*)&Vp[(j0 + jg + 3) * 128 + e8];
      const u32* p0 = (const u32*)&r0; const u32* p1 = (const u32*)&r1;
      const u32* p2 = (const u32*)&r2; const u32* p3 = (const u32*)&r3;
#pragma unroll
      for (int c = 0; c < 8; c++) {
        int w = c >> 1, sh = (c & 1) * 16;
        u32 lo = ((p0[w] >> sh) & 0xffffu) | (((p1[w] >> sh) & 0xffffu) << 16);
        u32 hi = ((p2[w] >> sh) & 0xffffu) | (((p3[w] >> sh) & 0xffffu) << 16);
        *(uint2*)&Vt[(e8 + c) * 72 + jg] = make_uint2(lo, hi);
      }
    }
    __syncthreads();
    short8 bK[4];
#pragma unroll
    for (int kk = 0; kk < 4; kk++)
      bK[kk] = *(const short8*)&Ks[(wv * 16 + cl) * 136 + kk * 32 + quad * 8];
    f32x4 st[4];
#pragma unroll
    for (int s = 0; s < 4; s++) {
      f32x4 acc = zero;
#pragma unroll
      for (int kk = 0; kk < 4; kk++) {
        short8 aQ = *(const short8*)&Qs[(s * 16 + cl) * 136 + kk * 32 + quad * 8];
        acc = __builtin_amdgcn_mfma_f32_16x16x32_bf16(aQ, bK[kk], acc, 0, 0, 0);
      }
      st[s] = acc;
    }
    float p[4][4];
    float tm = -1e30f;
#pragma unroll
    for (int s = 0; s < 4; s++)
#pragma unroll
      for (int r = 0; r < 4; r++) {
        float v = st[s][r];
        v = fmaxf(v, 0.2f * v);
        p[s][r] = v;
        tm = fmaxf(tm, v);
      }
    tm = fmaxf(tm, __shfl_xor(tm, 16));
    tm = fmaxf(tm, __shfl_xor(tm, 32));
    float mn = fmaxf(m_, tm);
    float alpha = __expf(m_ - mn);
    m_ = mn;
    float ps = 0.0f;
#pragma unroll
    for (int s = 0; s < 4; s++)
#pragma unroll
      for (int r = 0; r < 4; r++) {
        float e = __expf(p[s][r] - mn);
        p[s][r] = e;
        ps += e;
      }
    ps += __shfl_xor(ps, 16);
    ps += __shfl_xor(ps, 32);
    l_ = l_ * alpha + ps;
#pragma unroll
    for (int s = 0; s < 4; s++) {
      uint2 w2v = make_uint2(pack2(p[s][0], p[s][1]), pack2(p[s][2], p[s][3]));
      *(uint2*)&Pw[(wv * 16 + cl) * 72 + s * 16 + quad * 4] = w2v;
    }
    if (quad == 0) alphas[wv * 16 + cl] = alpha;
    __syncthreads();
    f32x4 av = *(const f32x4*)&alphas[wv * 16 + quad * 4];
#pragma unroll
    for (int es = 0; es < 8; es++) o[es] *= av;
    short8 aP[2];
#pragma unroll
    for (int k2 = 0; k2 < 2; k2++)
      aP[k2] = *(const short8*)&Pw[(wv * 16 + cl) * 72 + k2 * 32 + quad * 8];
#pragma unroll
    for (int es = 0; es < 8; es++) {
#pragma unroll
      for (int k2 = 0; k2 < 2; k2++) {
        short8 bV = *(const short8*)&Vt[(es * 16 + cl) * 72 + k2 * 32 + quad * 8];
        o[es] = __builtin_amdgcn_mfma_f32_16x16x32_bf16(aP[k2], bV, o[es], 0, 0, 0);
      }
    }
  }
#pragma unroll
  for (int es = 0; es < 8; es++)
#pragma unroll
    for (int r = 0; r < 4; r++)
      g_Opb[(b * 64 + wv * 16 + quad * 4 + r) * 128 + es * 16 + cl] = f2b(o[es][r]);
  if (quad == 0) {
    g_ml[(b * 64 + wv * 16 + cl) * 2 + 0] = m_;
    g_ml[(b * 64 + wv * 16 + cl) * 2 + 1] = l_;
  }
}

// ---------------- Kernel 4a: fused merge + att@fv_w1 via MFMA --------------------
// b = rt*8 + kc. head = kc; n = rt>>3; hn = kc*2+n; it = rt&7.
__global__ __launch_bounds__(256) void k_fv1() {
  __shared__ u16 atts[64 * 136];
  __shared__ u16 w1t[128 * 136];
  int b = blockIdx.x, tx = threadIdx.x;
  int kc = b & 7, rt = b >> 3;
  int r0 = rt * 64, k0 = kc * 128;
  int hn = kc * 2 + (rt >> 3), it = rt & 7;
  // stage w1^T chunk (coalesced from pre-transposed global)
#pragma unroll
  for (int t = 0; t < 8; t++) {
    int idx = t * 256 + tx, row = idx >> 4, oct = idx & 15;
    *(uint4*)&w1t[row * 136 + oct * 8] = *(const uint4*)&g_w1t[row * 1024 + k0 + oct * 8];
  }
  // merge 4 jc flash partials -> atts[row][e] (bf16), with leaky
  {
    int row = tx >> 2, cs = (tx & 3) * 32;
    float mc[4], lc[4];
#pragma unroll
    for (int c = 0; c < 4; c++) {
      float2 ml = *(const float2*)&g_ml[((hn * 32 + it * 4 + c) * 64 + row) * 2];
      mc[c] = ml.x; lc[c] = ml.y;
    }
    float ms = fmaxf(fmaxf(mc[0], mc[1]), fmaxf(mc[2], mc[3]));
    float lsum = 0.0f;
    float ra[32];
#pragma unroll
    for (int i = 0; i < 32; i++) ra[i] = 0.0f;
#pragma unroll
    for (int c = 0; c < 4; c++) {
      float w = __expf(mc[c] - ms);
      lsum += w * lc[c];
      const u16* src = &g_Opb[((hn * 32 + it * 4 + c) * 64 + row) * 128 + cs];
#pragma unroll
      for (int ov = 0; ov < 4; ov++) {
        uint4 v = *(const uint4*)&src[ov * 8];
        ra[ov * 8 + 0] = fmaf(w, lo16(v.x), ra[ov * 8 + 0]);
        ra[ov * 8 + 1] = fmaf(w, hi16(v.x), ra[ov * 8 + 1]);
        ra[ov * 8 + 2] = fmaf(w, lo16(v.y), ra[ov * 8 + 2]);
        ra[ov * 8 + 3] = fmaf(w, hi16(v.y), ra[ov * 8 + 3]);
        ra[ov * 8 + 4] = fmaf(w, lo16(v.z), ra[ov * 8 + 4]);
        ra[ov * 8 + 5] = fmaf(w, hi16(v.z), ra[ov * 8 + 5]);
        ra[ov * 8 + 6] = fmaf(w, lo16(v.w), ra[ov * 8 + 6]);
        ra[ov * 8 + 7] = fmaf(w, hi16(v.w), ra[ov * 8 + 7]);
      }
    }
    float inv = 1.0f / lsum;
    u32 pk[16];
#pragma unroll
    for (int i = 0; i < 16; i++) {
      float v0 = ra[i * 2] * inv;     v0 = fmaxf(v0, 0.2f * v0);
      float v1 = ra[i * 2 + 1] * inv; v1 = fmaxf(v1, 0.2f * v1);
      pk[i] = pack2(v0, v1);
    }
#pragma unroll
    for (int ov = 0; ov < 4; ov++)
      *(uint4*)&atts[row * 136 + cs + ov * 8] =
          make_uint4(pk[ov * 4], pk[ov * 4 + 1], pk[ov * 4 + 2], pk[ov * 4 + 3]);
  }
  __syncthreads();
  int lane = tx & 63, wv_ = tx >> 6, cl = lane & 15, quad = lane >> 4;
  short8 bA[4];
#pragma unroll
  for (int kk = 0; kk < 4; kk++)
    bA[kk] = *(const short8*)&atts[(wv_ * 16 + cl) * 136 + kk * 32 + quad * 8];
  f32x4 zero = {0.0f, 0.0f, 0.0f, 0.0f};
  f32x4 acc[8];
#pragma unroll
  for (int em = 0; em < 8; em++) acc[em] = zero;
#pragma unroll
  for (int em = 0; em < 8; em++)
#pragma unroll
    for (int kk = 0; kk < 4; kk++) {
      short8 aW = *(const short8*)&w1t[(em * 16 + cl) * 136 + kk * 32 + quad * 8];
      acc[em] = __builtin_amdgcn_mfma_f32_16x16x32_bf16(aW, bA[kk], acc[em], 0, 0, 0);
    }
#pragma unroll
  for (int em = 0; em < 8; em++)
    *(f32x4*)&g_part8[kc * 131072 + (r0 + wv_ * 16 + cl) * 128 + em * 16 + quad * 4] =
        acc[em];
}

// ---------------- Kernel 4b: bias+relu, @fv_w2, residual, A/B projections --------
__global__ void k_fv2(const float* __restrict__ b1, const float* __restrict__ w2,
                      const float* __restrict__ b2, const float* __restrict__ few1,
                      const float* __restrict__ feb1, float* __restrict__ x2out) {
  __shared__ float hids[2 * 128];
  __shared__ float x2s[2 * 128];
  __shared__ float red[8 * 256];
  int b = blockIdx.x, tx = threadIdx.x;
  int row0 = b * 2;
  {
    int r = tx >> 7, e = tx & 127;
    int gi = (row0 + r) * 128 + e;
    float s = b1[e];
#pragma unroll
    for (int kc = 0; kc < 8; kc++) s += g_part8[kc * 131072 + gi];
    hids[tx] = fmaxf(s, 0.0f);
  }
  __syncthreads();
  int ks = tx >> 5, eg = tx & 31;
  {
    float acc[2][4] = {};
#pragma unroll 4
    for (int i = 0; i < 16; i++) {
      int k = ks * 16 + i;
      float4 w4 = *(const float4*)&w2[k * 128 + eg * 4];
      float a0 = hids[k], a1 = hids[128 + k];
      acc[0][0] = fmaf(a0, w4.x, acc[0][0]); acc[0][1] = fmaf(a0, w4.y, acc[0][1]);
      acc[0][2] = fmaf(a0, w4.z, acc[0][2]); acc[0][3] = fmaf(a0, w4.w, acc[0][3]);
      acc[1][0] = fmaf(a1, w4.x, acc[1][0]); acc[1][1] = fmaf(a1, w4.y, acc[1][1]);
      acc[1][2] = fmaf(a1, w4.z, acc[1][2]); acc[1][3] = fmaf(a1, w4.w, acc[1][3]);
    }
#pragma unroll
    for (int r = 0; r < 2; r++)
      *(float4*)&red[ks * 256 + r * 128 + eg * 4] = *(float4*)acc[r];
  }
  __syncthreads();
  {
    float s = 0.0f;
#pragma unroll
    for (int k8 = 0; k8 < 8; k8++) s += red[k8 * 256 + tx];
    int r = tx >> 7, e = tx & 127;
    int gi = (row0 + r) * 128 + e;
    float c = s + b2[e] + g_h[gi];
    x2s[tx] = c;
    x2out[gi] = c;
  }
  __syncthreads();
  float aA[2][4] = {}, aB[2][4] = {};
#pragma unroll 4
  for (int i = 0; i < 16; i++) {
    int k = ks * 16 + i;
    float4 wa = *(const float4*)&few1[k * 128 + eg * 4];
    float4 wb = *(const float4*)&few1[(128 + k) * 128 + eg * 4];
    float a0 = x2s[k], a1 = x2s[128 + k];
    aA[0][0] = fmaf(a0, wa.x, aA[0][0]); aA[0][1] = fmaf(a0, wa.y, aA[0][1]);
    aA[0][2] = fmaf(a0, wa.z, aA[0][2]); aA[0][3] = fmaf(a0, wa.w, aA[0][3]);
    aA[1][0] = fmaf(a1, wa.x, aA[1][0]); aA[1][1] = fmaf(a1, wa.y, aA[1][1]);
    aA[1][2] = fmaf(a1, wa.z, aA[1][2]); aA[1][3] = fmaf(a1, wa.w, aA[1][3]);
    aB[0][0] = fmaf(a0, wb.x, aB[0][0]); aB[0][1] = fmaf(a0, wb.y, aB[0][1]);
    aB[0][2] = fmaf(a0, wb.z, aB[0][2]); aB[0][3] = fmaf(a0, wb.w, aB[0][3]);
    aB[1][0] = fmaf(a1, wb.x, aB[1][0]); aB[1][1] = fmaf(a1, wb.y, aB[1][1]);
    aB[1][2] = fmaf(a1, wb.z, aB[1][2]); aB[1][3] = fmaf(a1, wb.w, aB[1][3]);
  }
  __syncthreads();
#pragma unroll
  for (int r = 0; r < 2; r++)
    *(float4*)&red[ks * 256 + r * 128 + eg * 4] = *(float4*)aA[r];
  __syncthreads();
  {
    float s = 0.0f;
#pragma unroll
    for (int k8 = 0; k8 < 8; k8++) s += red[k8 * 256 + tx];
    int r = tx >> 7, e = tx & 127;
    g_A[(row0 + r) * 128 + e] = s + feb1[e];
  }
  __syncthreads();
#pragma unroll
  for (int r = 0; r < 2; r++)
    *(float4*)&red[ks * 256 + r * 128 + eg * 4] = *(float4*)aB[r];
  __syncthreads();
  {
    float s = 0.0f;
#pragma unroll
    for (int k8 = 0; k8 < 8; k8++) s += red[k8 * 256 + tx];
    int r = tx >> 7, e = tx & 127;
    g_Bm[(row0 + r) * 128 + e] = s;
  }
}

// ---------------- Kernel 5: pairwise edge FFN (A_i + B_j factorized) -------------
__global__ void k_edge(const float* __restrict__ few2, const float* __restrict__ feb2,
                       float* __restrict__ edge) {
  __shared__ float As[4 * 128];
  __shared__ float w2s[128];
  int b = blockIdx.x, tx = threadIdx.x;
  int n = b >> 8, rest = b & 255, ig = rest >> 1, jh = rest & 1;
  int i0 = ig * 4;
  if (tx < 128) w2s[tx] = few2[tx];
  As[tx] = g_A[(n * 512 + i0) * 128 + tx];
  As[tx + 256] = g_A[(n * 512 + i0) * 128 + tx + 256];
  float eb2 = feb2[0];
  __syncthreads();
  int j = jh * 256 + tx;
  const float* B0 = &g_Bm[(n * 512 + j) * 128];
  float acc[4] = {};
#pragma unroll 4
  for (int dc = 0; dc < 32; dc++) {
    float4 bv = *(const float4*)&B0[dc * 4];
    float4 w4 = *(const float4*)&w2s[dc * 4];
#pragma unroll
    for (int i = 0; i < 4; i++) {
      float4 a4 = *(const float4*)&As[i * 128 + dc * 4];
      acc[i] = fmaf(fmaxf(a4.x + bv.x, 0.0f), w4.x, acc[i]);
      acc[i] = fmaf(fmaxf(a4.y + bv.y, 0.0f), w4.y, acc[i]);
      acc[i] = fmaf(fmaxf(a4.z + bv.z, 0.0f), w4.z, acc[i]);
      acc[i] = fmaf(fmaxf(a4.w + bv.w, 0.0f), w4.w, acc[i]);
    }
  }
  const float scale = 1.0f / 512.0f;
#pragma unroll
  for (int i = 0; i < 4; i++)
    edge[(n * 512 + i0 + i) * 512 + j] = (acc[i] + eb2) * scale;
}

extern "C" void kernel_launch(void* const* d_in, const int* in_sizes, int n_in,
                              void* d_out, int out_size, void* d_ws, size_t ws_size,
                              hipStream_t stream) {
  (void)in_sizes; (void)n_in; (void)out_size; (void)d_ws; (void)ws_size;
  const float* x     = (const float*)d_in[0];
  const float* fn_w1 = (const float*)d_in[1];
  const float* fn_b1 = (const float*)d_in[2];
  const float* fn_w2 = (const float*)d_in[3];
  const float* fn_b2 = (const float*)d_in[4];
  const float* wk    = (const float*)d_in[5];
  const float* bk    = (const float*)d_in[6];
  const float* wq    = (const float*)d_in[7];
  const float* bq    = (const float*)d_in[8];
  const float* wv    = (const float*)d_in[9];
  const float* bv    = (const float*)d_in[10];
  const float* fv_w1 = (const float*)d_in[11];
  const float* fv_b1 = (const float*)d_in[12];
  const float* fv_w2 = (const float*)d_in[13];
  const float* fv_b2 = (const float*)d_in[14];
  const float* fe_w1 = (const float*)d_in[15];
  const float* fe_b1 = (const float*)d_in[16];
  const float* fe_w2 = (const float*)d_in[17];
  const float* fe_b2 = (const float*)d_in[18];

  float* x2out = (float*)d_out;      // [0, 131072) floats
  float* edge  = x2out + 131072;     // [131072, 655360) floats

  k_fnode<<<512, 256, 0, stream>>>(x, fn_w1, fn_b1, fn_w2, fn_b2, wk, wq, wv, fv_w1);
  k_kqv<<<384, 256, 0, stream>>>(bk, bq, bv);
  k_attn<<<512, 256, 0, stream>>>();
  k_fv1<<<128, 256, 0, stream>>>();
  k_fv2<<<512, 256, 0, stream>>>(fv_b1, fv_w2, fv_b2, fe_w1, fe_b1, x2out);
  k_edge<<<512, 256, 0, stream>>>(fe_w2, fe_b2, edge);
}